// Round 2
// baseline (943.035 us; speedup 1.0000x reference)
//
#include <hip/hip_runtime.h>
#include <math.h>

#define TT 2048
#define BB 32
#define EE 512
#define NN 512

typedef short bf16x8 __attribute__((ext_vector_type(8)));
typedef float f32x4 __attribute__((ext_vector_type(4)));

__device__ __forceinline__ short bf16_rne(float x) {
    const unsigned u = __float_as_uint(x);
    return (short)((u + 0x7FFFu + ((u >> 16) & 1u)) >> 16);
}
__device__ __forceinline__ float bf16_f32(short h) {
    return __uint_as_float(((unsigned)(unsigned short)h) << 16);
}
__device__ __forceinline__ void gload_lds16(const void* g, void* l) {
    __builtin_amdgcn_global_load_lds((const __attribute__((address_space(1))) void*)g,
                                     (__attribute__((address_space(3))) void*)l, 16, 0, 0);
}

// ---------------------------------------------------------------------------
// padding_mask dtype detector: int32 0/1 words stay <=1; byte-bool rows are
// monotonic so any packed word is 0x01000000/0x01010000/0x01010101/... (>1).
__global__ void detect_mask_kernel(const unsigned* __restrict__ pm, int* __restrict__ flag) {
    __shared__ int s[1024];
    const int l = threadIdx.x;
    int bad = 0;
    for (int i = l; i < BB * TT; i += 1024) bad |= (pm[i] > 1u);
    s[l] = bad;
    __syncthreads();
    for (int st = 512; st > 0; st >>= 1) { if (l < st) s[l] |= s[l + st]; __syncthreads(); }
    if (l == 0) *flag = s[0];
}

__device__ __forceinline__ int pad_at(const void* pm, int idx, int isByte) {
    return isByte ? (int)(((const unsigned char*)pm)[idx] != 0)
                  : (int)(((const int*)pm)[idx] != 0);
}

// ---------------------------------------------------------------------------
// padding_start[b] = count of not-pad = lengths[b]
__global__ void compute_ps_kernel(const void* __restrict__ pm, const int* __restrict__ flag,
                                  int* __restrict__ ps) {
    __shared__ int s[256];
    const int b = blockIdx.x, l = threadIdx.x;
    const int isByte = *flag;
    int cnt = 0;
    for (int t = l; t < TT; t += 256) cnt += (pad_at(pm, b * TT + t, isByte) == 0);
    s[l] = cnt;
    __syncthreads();
    for (int st = 128; st > 0; st >>= 1) { if (l < st) s[l] += s[l + st]; __syncthreads(); }
    if (l == 0) ps[b] = s[0];
}

// ---------------------------------------------------------------------------
// One-time W split+transpose: W[E][N] fp32 -> Wh/Wl[N][E] bf16 (k contiguous),
// RNE hi + RNE residual lo. Scratch lives in out_cif (overwritten later).
__global__ __launch_bounds__(256) void split_w_kernel(const float* __restrict__ W,
                                                      short* __restrict__ Wh,
                                                      short* __restrict__ Wl) {
    __shared__ float tile[32][33];
    const int bn = blockIdx.x, bk = blockIdx.y;
    const int tx = threadIdx.x & 31, ty = threadIdx.x >> 5;
    for (int i = ty; i < 32; i += 8)
        tile[i][tx] = W[(size_t)(bk * 32 + i) * NN + bn * 32 + tx];
    __syncthreads();
    for (int i = ty; i < 32; i += 8) {
        const float val = tile[tx][i];
        const short h = bf16_rne(val);
        const short lo = bf16_rne(val - bf16_f32(h));
        const size_t o = (size_t)(bn * 32 + i) * EE + bk * 32 + tx;
        Wh[o] = h;
        Wl[o] = lo;
    }
}

// ---------------------------------------------------------------------------
// MFMA GEMM + fused relu/dot(v)/sigmoid/mask.
// Split-bf16 3-term product: x*W ~= xh*Wh + xh*Wl + xl*Wh (each split RNE).
// Tile: BM=128 rows x BN=128 cols (nc loop x4 covers N=512), BK=64.
// 256 threads = 4 waves (2M x 2N), per-wave 64x64 via 16 x mfma_f32_16x16x32_bf16.
// LDS: A (reg-staged, on-the-fly split, XOR-swizzled ds_write_b128),
//      B (global_load_lds w/ pre-swizzled global source, m173 pattern).
// Swizzle: 16B-chunk index ^= (row&7)  -> frag ds_read_b128 2-way max (free).
__global__ __launch_bounds__(256, 2) void gemm_weight_mfma(
    const float* __restrict__ x, const void* __restrict__ pm, const int* __restrict__ flag,
    const short* __restrict__ Wh, const short* __restrict__ Wl,
    const float* __restrict__ bias, const float* __restrict__ v, const float* __restrict__ vb,
    float* __restrict__ weight_bt) {
    __shared__ __align__(16) short Ah[128 * 64];
    __shared__ __align__(16) short Al[128 * 64];
    __shared__ __align__(16) short Bh[128 * 64];
    __shared__ __align__(16) short Bl[128 * 64];
    __shared__ float bias_s[512], v_s[512];
    __shared__ float lsum[128][2];

    const int tid = threadIdx.x;
    const int l = tid & 63, wid = tid >> 6;
    const int wr = wid >> 1, wc = wid & 1;
    const int q = l >> 4, li = l & 15, x7 = l & 7;
    const int tp = blockIdx.x;

    for (int i = tid; i < 512; i += 256) { bias_s[i] = bias[i]; v_s[i] = v[i]; }

    const float* xblk = x + (size_t)tp * 128 * EE;
    // A staging coords: 2 threads per row, 32 elems (4 chunks of 8) each
    const int arow = tid >> 1;
    const int akoff = (tid & 1) * 32;
    const int ac0 = akoff >> 3;      // chunk base: 0 or 4
    const int aswz = arow & 7;

    float rowsum[4][4];
#pragma unroll
    for (int m = 0; m < 4; ++m)
#pragma unroll
        for (int r = 0; r < 4; ++r) rowsum[m][r] = 0.f;

    for (int nc = 0; nc < 4; ++nc) {
        const int n0 = nc * 128;
        f32x4 acc[4][4];
#pragma unroll
        for (int m = 0; m < 4; ++m)
#pragma unroll
            for (int n = 0; n < 4; ++n) acc[m][n] = (f32x4){0.f, 0.f, 0.f, 0.f};

        for (int k0 = 0; k0 < EE; k0 += 64) {
            __syncthreads();   // previous compute done; LDS free
            // --- stage B: 2x (128 rows x 64 k) bf16 via global_load_lds,
            //     source pre-swizzled so linear LDS dest + swizzled read match.
#pragma unroll
            for (int i = 0; i < 4; ++i) {
                const int u = i * 256 + tid;          // 16B unit id, lane-linear
                const int row = u >> 3, c = u & 7;
                const int ge = (n0 + row) * EE + k0 + ((c ^ (row & 7)) << 3);
                gload_lds16(Wh + ge, &Bh[u * 8]);
                gload_lds16(Wl + ge, &Bl[u * 8]);
            }
            // --- stage A: load fp32, RNE split, swizzled ds_write_b128
            const float* xr = xblk + (size_t)arow * EE + k0 + akoff;
#pragma unroll
            for (int g = 0; g < 4; ++g) {
                float e[8];
                *(float4*)&e[0] = *(const float4*)&xr[g * 8];
                *(float4*)&e[4] = *(const float4*)&xr[g * 8 + 4];
                bf16x8 hv, lv;
#pragma unroll
                for (int j = 0; j < 8; ++j) {
                    const short h = bf16_rne(e[j]);
                    hv[j] = h;
                    lv[j] = bf16_rne(e[j] - bf16_f32(h));
                }
                const int p = arow * 64 + (((ac0 + g) ^ aswz) << 3);
                *(bf16x8*)&Ah[p] = hv;
                *(bf16x8*)&Al[p] = lv;
            }
            __syncthreads();   // compiler drains vmcnt(0)+lgkmcnt(0) here
            // --- compute: 2 k-frags x (4m x 4n) x 3 terms = 96 mfma / wave
#pragma unroll
            for (int kf = 0; kf < 2; ++kf) {
                const int co = (((kf << 2) + q) ^ x7) << 3;
                bf16x8 ah[4], al[4];
#pragma unroll
                for (int m = 0; m < 4; ++m) {
                    const int ro = (wr * 64 + m * 16 + li) * 64 + co;
                    ah[m] = *(const bf16x8*)&Ah[ro];
                    al[m] = *(const bf16x8*)&Al[ro];
                }
#pragma unroll
                for (int n = 0; n < 4; ++n) {
                    const int bo = (wc * 64 + n * 16 + li) * 64 + co;
                    const bf16x8 bh = *(const bf16x8*)&Bh[bo];
                    const bf16x8 bl = *(const bf16x8*)&Bl[bo];
#pragma unroll
                    for (int m = 0; m < 4; ++m) {
                        acc[m][n] = __builtin_amdgcn_mfma_f32_16x16x32_bf16(ah[m], bh, acc[m][n], 0, 0, 0);
                        acc[m][n] = __builtin_amdgcn_mfma_f32_16x16x32_bf16(al[m], bh, acc[m][n], 0, 0, 0);
                        acc[m][n] = __builtin_amdgcn_mfma_f32_16x16x32_bf16(ah[m], bl, acc[m][n], 0, 0, 0);
                    }
                }
            }
        }
        // --- per-chunk epilogue: relu + dot(v), accumulate per-row partials.
        // C/D layout (m89-verified): col = lane&15, row = (lane>>4)*4 + reg.
#pragma unroll
        for (int m = 0; m < 4; ++m)
#pragma unroll
            for (int n = 0; n < 4; ++n) {
                const int col = n0 + wc * 64 + n * 16 + li;
                const float bcol = bias_s[col], vcol = v_s[col];
#pragma unroll
                for (int r = 0; r < 4; ++r) {
                    const float h = fmaxf(acc[m][n][r] + bcol, 0.f);
                    rowsum[m][r] = fmaf(h, vcol, rowsum[m][r]);
                }
            }
    }
    // reduce over the 16 columns held per lane-group (lanes sharing l>>4)
#pragma unroll
    for (int m = 0; m < 4; ++m)
#pragma unroll
        for (int r = 0; r < 4; ++r) {
            float s = rowsum[m][r];
            s += __shfl_xor(s, 1, 64);
            s += __shfl_xor(s, 2, 64);
            s += __shfl_xor(s, 4, 64);
            s += __shfl_xor(s, 8, 64);
            rowsum[m][r] = s;
        }
    if (li == 0) {
#pragma unroll
        for (int m = 0; m < 4; ++m)
#pragma unroll
            for (int r = 0; r < 4; ++r)
                lsum[wr * 64 + m * 16 + q * 4 + r][wc] = rowsum[m][r];
    }
    __syncthreads();
    if (tid < 128) {
        const int isByte = *flag;
        const float logit = lsum[tid][0] + lsum[tid][1] + *vb;   // deterministic order
        const float wg = 1.0f / (1.0f + expf(-logit));
        const int gr = tp * 128 + tid;
        const int t = gr >> 5, b = gr & 31;
        weight_bt[(size_t)b * TT + t] = pad_at(pm, b * TT + t, isByte) ? 0.f : wg;
    }
}

// ---------------------------------------------------------------------------
// Sequential scalar scan, one block per batch. Weights staged through LDS;
// lane 0 runs the serial fp32 recurrence. NEW: near-threshold fire decisions
// (|prev_w + w - 1| < BAND, ~1 event/row) trigger a cooperative full-fp32
// recompute of that single weight, killing the bf16-GEMM fire-flip risk.
#define CH 512
#define MAXREC 2080
#define BAND 2.5e-4f
__global__ __launch_bounds__(64) void cif_scan_kernel(
    const float* __restrict__ weight_bt, const int* __restrict__ ps_arr,
    const float* __restrict__ x, const float* __restrict__ W,
    const float* __restrict__ bias, const float* __restrict__ v,
    const float* __restrict__ vb,
    float* __restrict__ cc_bt, float4* __restrict__ recs,
    int* __restrict__ nfr, float* __restrict__ out_q, float* __restrict__ out_marks) {
    __shared__ float wsm[CH];
    __shared__ float ccs[CH];
    __shared__ float mks[CH];
    __shared__ float xrow[EE];
    __shared__ float4 recs_s[MAXREC];
    __shared__ int m_sh, ev_sh;
    const int b = blockIdx.x, l = threadIdx.x;
    const int ps = ps_arr[b];
    const float* wrow = weight_bt + (size_t)b * TT;

    // persistent scalar state (lane 0's registers survive across chunks)
    float prev_w = 0.f, fc = 0.f;
    int m = 0, t_first = 0, cur = 0, last_fixed = -1;
    float qpart = 0.f;   // per-lane partial of sum(w)

    for (int t0 = 0; t0 < TT; t0 += CH) {
        // stage chunk: 64 lanes x 8 floats = 512
        const float4 la = *(const float4*)&wrow[t0 + l * 8];
        const float4 lb = *(const float4*)&wrow[t0 + l * 8 + 4];
        *(float4*)&wsm[l * 8]     = la;
        *(float4*)&wsm[l * 8 + 4] = lb;
        qpart += la.x + la.y + la.z + la.w + lb.x + lb.y + lb.z + lb.w;
        __syncthreads();
        while (true) {
            if (l == 0) {
                int ev = -1;
                while (cur < t0 + CH) {
                    const int i = cur - t0;
                    const float w0 = wsm[i];
                    if (w0 > 0.f && cur != last_fixed &&
                        fabsf(prev_w + w0 - 1.0f) < BAND) { ev = cur; break; }
                    const int t = cur;
                    if (t == 0) fc = w0;
                    float mark = 0.f;
                    const bool fired = (prev_w + w0 >= 1.0f);
                    const float remained = 1.0f - prev_w;
                    if (fired) {
                        ccs[i] = remained;
                        recs_s[m] = make_float4(__int_as_float(t_first), __int_as_float(t), fc, 1.0f);
                        mark = 1.f;
                        ++m;
                        t_first = t;
                        fc = w0 - remained;
                        prev_w = w0 - remained;
                    } else {
                        ccs[i] = w0;
                        prev_w += w0;
                    }
                    if (t == ps && prev_w > 0.6f) {
                        recs_s[m] = make_float4(__int_as_float(t_first), __int_as_float(t - 1),
                                                fc, 1.0f / (prev_w + 1e-10f));
                        mark = 1.f;
                        ++m;
                    }
                    mks[i] = mark;
                    ++cur;
                }
                ev_sh = ev;
                if (ev < 0) m_sh = m;
            }
            __syncthreads();
            const int ev = ev_sh;
            if (ev < 0) break;
            // --- cooperative full-fp32 recompute of weight(b, ev), 64 lanes
            {
                const float* xr = &x[((size_t)ev * BB + b) * EE];
                *(float4*)&xrow[l * 8]     = *(const float4*)&xr[l * 8];
                *(float4*)&xrow[l * 8 + 4] = *(const float4*)&xr[l * 8 + 4];
                __syncthreads();
                float part = 0.f;
                for (int jj = 0; jj < 8; ++jj) {
                    const int j = jj * 64 + l;       // coalesced W reads per e
                    float h = bias[j];
                    for (int e = 0; e < EE; ++e) h = fmaf(xrow[e], W[(size_t)e * NN + j], h);
                    part = fmaf(fmaxf(h, 0.f), v[j], part);
                }
#pragma unroll
                for (int s = 32; s >= 1; s >>= 1) part += __shfl_xor(part, s, 64);
                if (l == 0) {
                    wsm[ev - t0] = 1.0f / (1.0f + expf(-(part + *vb)));
                    last_fixed = ev;
                }
                __syncthreads();
            }
        }
        // flush chunk coalesced (barrier above ordered lane0's ccs/mks writes)
        *(float4*)&cc_bt[(size_t)b * TT + t0 + l * 8]     = *(const float4*)&ccs[l * 8];
        *(float4*)&cc_bt[(size_t)b * TT + t0 + l * 8 + 4] = *(const float4*)&ccs[l * 8 + 4];
        *(float4*)&out_marks[(size_t)b * TT + t0 + l * 8]     = *(const float4*)&mks[l * 8];
        *(float4*)&out_marks[(size_t)b * TT + t0 + l * 8 + 4] = *(const float4*)&mks[l * 8 + 4];
        __syncthreads();
    }
    // flush recs coalesced
    const int mtot = m_sh;
    for (int j = l; j < mtot; j += 64) recs[b * TT + j] = recs_s[j];
    // qsum reduction
#pragma unroll
    for (int s = 32; s >= 1; s >>= 1) qpart += __shfl_xor(qpart, s, 64);
    if (l == 0) { out_q[b] = qpart; nfr[b] = mtot; }
}

// ---------------------------------------------------------------------------
// Parallel frame materialization: block (j, b) -> compacted slot j of batch b.
__global__ __launch_bounds__(128) void cif_out_kernel(
    const float* __restrict__ x, const float* __restrict__ cc_bt,
    const float4* __restrict__ recs, const int* __restrict__ nfr,
    float* __restrict__ out_cif, float* __restrict__ out_mask) {
    const int j = blockIdx.x, b = blockIdx.y;
    const int l = threadIdx.x;
    const int m = nfr[b];
    float4 acc = make_float4(0.f, 0.f, 0.f, 0.f);
    const size_t obase = ((size_t)b * TT + j) * EE + l * 4;
    if (j < m) {
        const float4 r = recs[b * TT + j];
        const int t0 = __float_as_int(r.x);
        const int t1 = __float_as_int(r.y);
        const float fcoef = r.z, scale = r.w;
        for (int t = t0; t <= t1; ++t) {
            const float coeff = (t == t0) ? fcoef : cc_bt[(size_t)b * TT + t];
            const float4 xv = *(const float4*)&x[((size_t)t * BB + b) * EE + l * 4];
            acc.x = fmaf(coeff, xv.x, acc.x);
            acc.y = fmaf(coeff, xv.y, acc.y);
            acc.z = fmaf(coeff, xv.z, acc.z);
            acc.w = fmaf(coeff, xv.w, acc.w);
        }
        acc.x *= scale; acc.y *= scale; acc.z *= scale; acc.w *= scale;
        if (l == 0) out_mask[b * TT + j] = 1.f;
    } else {
        if (l == 0) out_mask[b * TT + j] = 0.f;
    }
    *(float4*)&out_cif[obase] = acc;
}

// ---------------------------------------------------------------------------
extern "C" void kernel_launch(void* const* d_in, const int* in_sizes, int n_in,
                              void* d_out, int out_size, void* d_ws, size_t ws_size,
                              hipStream_t stream) {
    const float* x    = (const float*)d_in[0];   // (T, B, E)
    const void*  pm   = d_in[1];                 // (B, T) bool -> int32 or bytes (detected)
    const float* W    = (const float*)d_in[2];   // (E, N)
    const float* bias = (const float*)d_in[3];   // (N,)
    const float* v    = (const float*)d_in[4];   // (N, 1)
    const float* vb   = (const float*)d_in[5];   // (1,)

    // workspace: same footprint class as the proven round-0 kernel (~1.5 MB)
    float* ws        = (float*)d_ws;
    float* weight_bt = ws;                                 // BB*TT
    float* cc_bt     = ws + (size_t)TT * BB;               // BB*TT
    float4* recs     = (float4*)(ws + 2 * (size_t)TT * BB);// BB*TT float4
    int* nfr         = (int*)(ws + 2 * (size_t)TT * BB + 4 * (size_t)BB * TT);
    int* ps          = nfr + BB;
    int* flag        = ps + BB;

    float* out_cif   = (float*)d_out;                     // (B, T, E)
    float* out_mask  = out_cif + (size_t)BB * TT * EE;    // (B, T)
    float* out_q     = out_mask + (size_t)BB * TT;        // (B,)
    float* out_marks = out_q + BB;                        // (B, T)

    // W-split scratch lives in out_cif (1 MB of 128 MB); gemm consumes it
    // before cif_out_kernel overwrites every byte of out_cif (stream-ordered).
    short* Whs = (short*)out_cif;                         // 512 KB
    short* Wls = Whs + (size_t)NN * EE;                   // 512 KB

    detect_mask_kernel<<<1, 1024, 0, stream>>>((const unsigned*)pm, flag);
    compute_ps_kernel<<<BB, 256, 0, stream>>>(pm, flag, ps);
    split_w_kernel<<<dim3(16, 16), 256, 0, stream>>>(W, Whs, Wls);
    gemm_weight_mfma<<<512, 256, 0, stream>>>(x, pm, flag, Whs, Wls, bias, v, vb, weight_bt);
    cif_scan_kernel<<<BB, 64, 0, stream>>>(weight_bt, ps, x, W, bias, v, vb,
                                           cc_bt, recs, nfr, out_q, out_marks);
    cif_out_kernel<<<dim3(TT, BB), 128, 0, stream>>>(x, cc_bt, recs, nfr, out_cif, out_mask);
}

// Round 3
// 884.528 us; speedup vs baseline: 1.0661x; 1.0661x over previous
//
#include <hip/hip_runtime.h>
#include <math.h>

#define TT 2048
#define BB 32
#define EE 512
#define NN 512

typedef short bf16x8 __attribute__((ext_vector_type(8)));
typedef float f32x4 __attribute__((ext_vector_type(4)));

__device__ __forceinline__ short bf16_rne(float x) {
    const unsigned u = __float_as_uint(x);
    return (short)((u + 0x7FFFu + ((u >> 16) & 1u)) >> 16);
}
__device__ __forceinline__ float bf16_f32(short h) {
    return __uint_as_float(((unsigned)(unsigned short)h) << 16);
}
__device__ __forceinline__ void gload_lds16(const void* g, void* l) {
    __builtin_amdgcn_global_load_lds((const __attribute__((address_space(1))) void*)g,
                                     (__attribute__((address_space(3))) void*)l, 16, 0, 0);
}

// ---------------------------------------------------------------------------
// padding_mask dtype detector: int32 0/1 words stay <=1; byte-bool rows are
// monotonic so any packed word is 0x01000000/0x01010000/0x01010101/... (>1).
__global__ void detect_mask_kernel(const unsigned* __restrict__ pm, int* __restrict__ flag) {
    __shared__ int s[1024];
    const int l = threadIdx.x;
    int bad = 0;
    for (int i = l; i < BB * TT; i += 1024) bad |= (pm[i] > 1u);
    s[l] = bad;
    __syncthreads();
    for (int st = 512; st > 0; st >>= 1) { if (l < st) s[l] |= s[l + st]; __syncthreads(); }
    if (l == 0) *flag = s[0];
}

__device__ __forceinline__ int pad_at(const void* pm, int idx, int isByte) {
    return isByte ? (int)(((const unsigned char*)pm)[idx] != 0)
                  : (int)(((const int*)pm)[idx] != 0);
}

// ---------------------------------------------------------------------------
// padding_start[b] = count of not-pad = lengths[b]
__global__ void compute_ps_kernel(const void* __restrict__ pm, const int* __restrict__ flag,
                                  int* __restrict__ ps) {
    __shared__ int s[256];
    const int b = blockIdx.x, l = threadIdx.x;
    const int isByte = *flag;
    int cnt = 0;
    for (int t = l; t < TT; t += 256) cnt += (pad_at(pm, b * TT + t, isByte) == 0);
    s[l] = cnt;
    __syncthreads();
    for (int st = 128; st > 0; st >>= 1) { if (l < st) s[l] += s[l + st]; __syncthreads(); }
    if (l == 0) ps[b] = s[0];
}

// ---------------------------------------------------------------------------
// One-time W split+transpose: W[E][N] fp32 -> Wh/Wl[N][E] bf16 (k contiguous),
// RNE hi + RNE residual lo. Scratch lives in out_cif (overwritten later).
__global__ __launch_bounds__(256) void split_w_kernel(const float* __restrict__ W,
                                                      short* __restrict__ Wh,
                                                      short* __restrict__ Wl) {
    __shared__ float tile[32][33];
    const int bn = blockIdx.x, bk = blockIdx.y;
    const int tx = threadIdx.x & 31, ty = threadIdx.x >> 5;
    for (int i = ty; i < 32; i += 8)
        tile[i][tx] = W[(size_t)(bk * 32 + i) * NN + bn * 32 + tx];
    __syncthreads();
    for (int i = ty; i < 32; i += 8) {
        const float val = tile[tx][i];
        const short h = bf16_rne(val);
        const short lo = bf16_rne(val - bf16_f32(h));
        const size_t o = (size_t)(bn * 32 + i) * EE + bk * 32 + tx;
        Wh[o] = h;
        Wl[o] = lo;
    }
}

// ---------------------------------------------------------------------------
// MFMA GEMM + fused relu/dot(v)/sigmoid/mask.
// Split-bf16 3-term product: x*W ~= xh*Wh + xh*Wl + xl*Wh (each split RNE).
// Tile: BM=128 rows x BN=128 cols (nc loop x4 covers N=512), BK=64.
// 256 threads = 4 waves (2M x 2N), per-wave 64x64 via 16 x mfma_f32_16x16x32_bf16.
// LDS: A (reg-staged, on-the-fly split, XOR-swizzled ds_write_b128),
//      B (global_load_lds w/ pre-swizzled global source, m173 pattern).
// Swizzle: 16B-chunk index ^= (row&7)  -> frag ds_read_b128 2-way max (free).
__global__ __launch_bounds__(256, 2) void gemm_weight_mfma(
    const float* __restrict__ x, const void* __restrict__ pm, const int* __restrict__ flag,
    const short* __restrict__ Wh, const short* __restrict__ Wl,
    const float* __restrict__ bias, const float* __restrict__ v, const float* __restrict__ vb,
    float* __restrict__ weight_bt) {
    __shared__ __align__(16) short Ah[128 * 64];
    __shared__ __align__(16) short Al[128 * 64];
    __shared__ __align__(16) short Bh[128 * 64];
    __shared__ __align__(16) short Bl[128 * 64];
    __shared__ float bias_s[512], v_s[512];
    __shared__ float lsum[128][2];

    const int tid = threadIdx.x;
    const int l = tid & 63, wid = tid >> 6;
    const int wr = wid >> 1, wc = wid & 1;
    const int q = l >> 4, li = l & 15, x7 = l & 7;
    const int tp = blockIdx.x;

    for (int i = tid; i < 512; i += 256) { bias_s[i] = bias[i]; v_s[i] = v[i]; }

    const float* xblk = x + (size_t)tp * 128 * EE;
    // A staging coords: 2 threads per row, 32 elems (4 chunks of 8) each
    const int arow = tid >> 1;
    const int akoff = (tid & 1) * 32;
    const int ac0 = akoff >> 3;      // chunk base: 0 or 4
    const int aswz = arow & 7;

    float rowsum[4][4];
#pragma unroll
    for (int m = 0; m < 4; ++m)
#pragma unroll
        for (int r = 0; r < 4; ++r) rowsum[m][r] = 0.f;

    for (int nc = 0; nc < 4; ++nc) {
        const int n0 = nc * 128;
        f32x4 acc[4][4];
#pragma unroll
        for (int m = 0; m < 4; ++m)
#pragma unroll
            for (int n = 0; n < 4; ++n) acc[m][n] = (f32x4){0.f, 0.f, 0.f, 0.f};

        for (int k0 = 0; k0 < EE; k0 += 64) {
            __syncthreads();   // previous compute done; LDS free
            // --- stage B: 2x (128 rows x 64 k) bf16 via global_load_lds,
            //     source pre-swizzled so linear LDS dest + swizzled read match.
#pragma unroll
            for (int i = 0; i < 4; ++i) {
                const int u = i * 256 + tid;          // 16B unit id, lane-linear
                const int row = u >> 3, c = u & 7;
                const int ge = (n0 + row) * EE + k0 + ((c ^ (row & 7)) << 3);
                gload_lds16(Wh + ge, &Bh[u * 8]);
                gload_lds16(Wl + ge, &Bl[u * 8]);
            }
            // --- stage A: load fp32, RNE split, swizzled ds_write_b128
            const float* xr = xblk + (size_t)arow * EE + k0 + akoff;
#pragma unroll
            for (int g = 0; g < 4; ++g) {
                float e[8];
                *(float4*)&e[0] = *(const float4*)&xr[g * 8];
                *(float4*)&e[4] = *(const float4*)&xr[g * 8 + 4];
                bf16x8 hv, lv;
#pragma unroll
                for (int j = 0; j < 8; ++j) {
                    const short h = bf16_rne(e[j]);
                    hv[j] = h;
                    lv[j] = bf16_rne(e[j] - bf16_f32(h));
                }
                const int p = arow * 64 + (((ac0 + g) ^ aswz) << 3);
                *(bf16x8*)&Ah[p] = hv;
                *(bf16x8*)&Al[p] = lv;
            }
            __syncthreads();   // compiler drains vmcnt(0)+lgkmcnt(0) here
            // --- compute: 2 k-frags x (4m x 4n) x 3 terms = 96 mfma / wave
#pragma unroll
            for (int kf = 0; kf < 2; ++kf) {
                const int co = (((kf << 2) + q) ^ x7) << 3;
                bf16x8 ah[4], al[4];
#pragma unroll
                for (int m = 0; m < 4; ++m) {
                    const int ro = (wr * 64 + m * 16 + li) * 64 + co;
                    ah[m] = *(const bf16x8*)&Ah[ro];
                    al[m] = *(const bf16x8*)&Al[ro];
                }
#pragma unroll
                for (int n = 0; n < 4; ++n) {
                    const int bo = (wc * 64 + n * 16 + li) * 64 + co;
                    const bf16x8 bh = *(const bf16x8*)&Bh[bo];
                    const bf16x8 bl = *(const bf16x8*)&Bl[bo];
#pragma unroll
                    for (int m = 0; m < 4; ++m) {
                        acc[m][n] = __builtin_amdgcn_mfma_f32_16x16x32_bf16(ah[m], bh, acc[m][n], 0, 0, 0);
                        acc[m][n] = __builtin_amdgcn_mfma_f32_16x16x32_bf16(al[m], bh, acc[m][n], 0, 0, 0);
                        acc[m][n] = __builtin_amdgcn_mfma_f32_16x16x32_bf16(ah[m], bl, acc[m][n], 0, 0, 0);
                    }
                }
            }
        }
        // --- per-chunk epilogue: relu + dot(v), accumulate per-row partials.
        // C/D layout (m89-verified): col = lane&15, row = (lane>>4)*4 + reg.
#pragma unroll
        for (int m = 0; m < 4; ++m)
#pragma unroll
            for (int n = 0; n < 4; ++n) {
                const int col = n0 + wc * 64 + n * 16 + li;
                const float bcol = bias_s[col], vcol = v_s[col];
#pragma unroll
                for (int r = 0; r < 4; ++r) {
                    const float h = fmaxf(acc[m][n][r] + bcol, 0.f);
                    rowsum[m][r] = fmaf(h, vcol, rowsum[m][r]);
                }
            }
    }
    // reduce over the 16 columns held per lane-group (lanes sharing l>>4)
#pragma unroll
    for (int m = 0; m < 4; ++m)
#pragma unroll
        for (int r = 0; r < 4; ++r) {
            float s = rowsum[m][r];
            s += __shfl_xor(s, 1, 64);
            s += __shfl_xor(s, 2, 64);
            s += __shfl_xor(s, 4, 64);
            s += __shfl_xor(s, 8, 64);
            rowsum[m][r] = s;
        }
    if (li == 0) {
#pragma unroll
        for (int m = 0; m < 4; ++m)
#pragma unroll
            for (int r = 0; r < 4; ++r)
                lsum[wr * 64 + m * 16 + q * 4 + r][wc] = rowsum[m][r];
    }
    __syncthreads();
    if (tid < 128) {
        const int isByte = *flag;
        const float logit = lsum[tid][0] + lsum[tid][1] + *vb;   // deterministic order
        const float wg = 1.0f / (1.0f + expf(-logit));
        const int gr = tp * 128 + tid;
        const int t = gr >> 5, b = gr & 31;
        weight_bt[(size_t)b * TT + t] = pad_at(pm, b * TT + t, isByte) ? 0.f : wg;
    }
}

// ---------------------------------------------------------------------------
// Sequential scalar scan, one block per batch. Lane 0 runs the serial fp32
// recurrence BATCHED: 8 weights per 2x ds_read_b128, all-register unrolled
// body (round-0 speed). Near-threshold fire decisions (|prev_w+w-1| < BAND,
// ~1/row) are detected in-line for ~2 extra VALU/step; on detection the
// 4-word scalar state snapshot is rewound to the group start, all 64 lanes
// recompute that single weight in full fp32, and the group re-runs (group
// writes are idempotent; transient recs_s overshoot stays within MAXREC).
#define CH 512
#define MAXREC 2080
#define BAND 2.5e-4f
__global__ __launch_bounds__(64) void cif_scan_kernel(
    const float* __restrict__ weight_bt, const int* __restrict__ ps_arr,
    const float* __restrict__ x, const float* __restrict__ W,
    const float* __restrict__ bias, const float* __restrict__ v,
    const float* __restrict__ vb,
    float* __restrict__ cc_bt, float4* __restrict__ recs,
    int* __restrict__ nfr, float* __restrict__ out_q, float* __restrict__ out_marks) {
    __shared__ float wsm[CH];
    __shared__ float ccs[CH];
    __shared__ float mks[CH];
    __shared__ float xrow[EE];
    __shared__ float4 recs_s[MAXREC];
    __shared__ int m_sh, ev_sh;
    const int b = blockIdx.x, l = threadIdx.x;
    const int ps = ps_arr[b];
    const float* wrow = weight_bt + (size_t)b * TT;

    // persistent scalar state (lane 0's registers survive across chunks)
    float prev_w = 0.f, fc = 0.f;
    int m = 0, t_first = 0, cur = 0, last_fixed = -1;
    float qpart = 0.f;   // per-lane partial of sum(w)

    for (int t0 = 0; t0 < TT; t0 += CH) {
        // stage chunk: 64 lanes x 8 floats = 512
        const float4 la = *(const float4*)&wrow[t0 + l * 8];
        const float4 lb = *(const float4*)&wrow[t0 + l * 8 + 4];
        *(float4*)&wsm[l * 8]     = la;
        *(float4*)&wsm[l * 8 + 4] = lb;
        qpart += la.x + la.y + la.z + la.w + lb.x + lb.y + lb.z + lb.w;
        __syncthreads();
        for (;;) {
            if (l == 0) {
                int ev = -1;
                while (cur < t0 + CH) {
                    const int i = cur - t0;                 // always group-aligned
                    const float4 wa = *(const float4*)&wsm[i];
                    const float4 wb = *(const float4*)&wsm[i + 4];
                    const float wv[8] = {wa.x, wa.y, wa.z, wa.w, wb.x, wb.y, wb.z, wb.w};
                    const float sp_w = prev_w, sp_fc = fc;  // snapshot for rewind
                    const int sp_m = m, sp_tf = t_first;
                    int evu = -1;
#pragma unroll
                    for (int u = 0; u < 8; ++u) {
                        const int t = cur + u;
                        const float w = wv[u];
                        const float s = prev_w + w;
                        if (evu < 0 && w > 0.f && t > last_fixed && fabsf(s - 1.0f) < BAND)
                            evu = u;
                        if (t == 0) fc = w;
                        float mark = 0.f;
                        const bool fired = (s >= 1.0f);
                        const float remained = 1.0f - prev_w;
                        if (fired) {
                            ccs[i + u] = remained;
                            recs_s[m] = make_float4(__int_as_float(t_first), __int_as_float(t), fc, 1.0f);
                            mark = 1.f;
                            ++m;
                            t_first = t;
                            fc = w - remained;
                            prev_w = w - remained;
                        } else {
                            ccs[i + u] = w;
                            prev_w = s;
                        }
                        if (t == ps && prev_w > 0.6f) {
                            recs_s[m] = make_float4(__int_as_float(t_first), __int_as_float(t - 1),
                                                    fc, 1.0f / (prev_w + 1e-10f));
                            mark = 1.f;
                            ++m;
                        }
                        mks[i + u] = mark;
                    }
                    if (evu >= 0) {                          // rare: rewind + request fix
                        prev_w = sp_w; fc = sp_fc; m = sp_m; t_first = sp_tf;
                        ev = cur + evu;
                        break;
                    }
                    cur += 8;
                }
                ev_sh = ev;
                if (ev < 0) m_sh = m;
            }
            __syncthreads();
            const int ev = ev_sh;
            if (ev < 0) break;
            // --- cooperative full-fp32 recompute of weight(b, ev), 64 lanes
            {
                const float* xr = &x[((size_t)ev * BB + b) * EE];
                *(float4*)&xrow[l * 8]     = *(const float4*)&xr[l * 8];
                *(float4*)&xrow[l * 8 + 4] = *(const float4*)&xr[l * 8 + 4];
                __syncthreads();
                float part = 0.f;
                for (int jj = 0; jj < 8; ++jj) {
                    const int j = jj * 64 + l;       // coalesced W reads per e
                    float h = bias[j];
                    for (int e = 0; e < EE; ++e) h = fmaf(xrow[e], W[(size_t)e * NN + j], h);
                    part = fmaf(fmaxf(h, 0.f), v[j], part);
                }
#pragma unroll
                for (int s = 32; s >= 1; s >>= 1) part += __shfl_xor(part, s, 64);
                if (l == 0) {
                    wsm[ev - t0] = 1.0f / (1.0f + expf(-(part + *vb)));
                    last_fixed = ev;                 // fixes are monotone in t
                }
                __syncthreads();
            }
        }
        // flush chunk coalesced (barrier above ordered lane0's ccs/mks writes)
        *(float4*)&cc_bt[(size_t)b * TT + t0 + l * 8]     = *(const float4*)&ccs[l * 8];
        *(float4*)&cc_bt[(size_t)b * TT + t0 + l * 8 + 4] = *(const float4*)&ccs[l * 8 + 4];
        *(float4*)&out_marks[(size_t)b * TT + t0 + l * 8]     = *(const float4*)&mks[l * 8];
        *(float4*)&out_marks[(size_t)b * TT + t0 + l * 8 + 4] = *(const float4*)&mks[l * 8 + 4];
        __syncthreads();
    }
    // flush recs coalesced
    const int mtot = m_sh;
    for (int j = l; j < mtot; j += 64) recs[b * TT + j] = recs_s[j];
    // qsum reduction
#pragma unroll
    for (int s = 32; s >= 1; s >>= 1) qpart += __shfl_xor(qpart, s, 64);
    if (l == 0) { out_q[b] = qpart; nfr[b] = mtot; }
}

// ---------------------------------------------------------------------------
// Parallel frame materialization: block (j, b) -> compacted slot j of batch b.
__global__ __launch_bounds__(128) void cif_out_kernel(
    const float* __restrict__ x, const float* __restrict__ cc_bt,
    const float4* __restrict__ recs, const int* __restrict__ nfr,
    float* __restrict__ out_cif, float* __restrict__ out_mask) {
    const int j = blockIdx.x, b = blockIdx.y;
    const int l = threadIdx.x;
    const int m = nfr[b];
    float4 acc = make_float4(0.f, 0.f, 0.f, 0.f);
    const size_t obase = ((size_t)b * TT + j) * EE + l * 4;
    if (j < m) {
        const float4 r = recs[b * TT + j];
        const int t0 = __float_as_int(r.x);
        const int t1 = __float_as_int(r.y);
        const float fcoef = r.z, scale = r.w;
        for (int t = t0; t <= t1; ++t) {
            const float coeff = (t == t0) ? fcoef : cc_bt[(size_t)b * TT + t];
            const float4 xv = *(const float4*)&x[((size_t)t * BB + b) * EE + l * 4];
            acc.x = fmaf(coeff, xv.x, acc.x);
            acc.y = fmaf(coeff, xv.y, acc.y);
            acc.z = fmaf(coeff, xv.z, acc.z);
            acc.w = fmaf(coeff, xv.w, acc.w);
        }
        acc.x *= scale; acc.y *= scale; acc.z *= scale; acc.w *= scale;
        if (l == 0) out_mask[b * TT + j] = 1.f;
    } else {
        if (l == 0) out_mask[b * TT + j] = 0.f;
    }
    *(float4*)&out_cif[obase] = acc;
}

// ---------------------------------------------------------------------------
extern "C" void kernel_launch(void* const* d_in, const int* in_sizes, int n_in,
                              void* d_out, int out_size, void* d_ws, size_t ws_size,
                              hipStream_t stream) {
    const float* x    = (const float*)d_in[0];   // (T, B, E)
    const void*  pm   = d_in[1];                 // (B, T) bool -> int32 or bytes (detected)
    const float* W    = (const float*)d_in[2];   // (E, N)
    const float* bias = (const float*)d_in[3];   // (N,)
    const float* v    = (const float*)d_in[4];   // (N, 1)
    const float* vb   = (const float*)d_in[5];   // (1,)

    // workspace: same footprint class as the proven round-0 kernel (~1.5 MB)
    float* ws        = (float*)d_ws;
    float* weight_bt = ws;                                 // BB*TT
    float* cc_bt     = ws + (size_t)TT * BB;               // BB*TT
    float4* recs     = (float4*)(ws + 2 * (size_t)TT * BB);// BB*TT float4
    int* nfr         = (int*)(ws + 2 * (size_t)TT * BB + 4 * (size_t)BB * TT);
    int* ps          = nfr + BB;
    int* flag        = ps + BB;

    float* out_cif   = (float*)d_out;                     // (B, T, E)
    float* out_mask  = out_cif + (size_t)BB * TT * EE;    // (B, T)
    float* out_q     = out_mask + (size_t)BB * TT;        // (B,)
    float* out_marks = out_q + BB;                        // (B, T)

    // W-split scratch lives in out_cif (1 MB of 128 MB); gemm consumes it
    // before cif_out_kernel overwrites every byte of out_cif (stream-ordered).
    short* Whs = (short*)out_cif;                         // 512 KB
    short* Wls = Whs + (size_t)NN * EE;                   // 512 KB

    detect_mask_kernel<<<1, 1024, 0, stream>>>((const unsigned*)pm, flag);
    compute_ps_kernel<<<BB, 256, 0, stream>>>(pm, flag, ps);
    split_w_kernel<<<dim3(16, 16), 256, 0, stream>>>(W, Whs, Wls);
    gemm_weight_mfma<<<512, 256, 0, stream>>>(x, pm, flag, Whs, Wls, bias, v, vb, weight_bt);
    cif_scan_kernel<<<BB, 64, 0, stream>>>(weight_bt, ps, x, W, bias, v, vb,
                                           cc_bt, recs, nfr, out_q, out_marks);
    cif_out_kernel<<<dim3(TT, BB), 128, 0, stream>>>(x, cc_bt, recs, nfr, out_cif, out_mask);
}

// Round 4
// 751.817 us; speedup vs baseline: 1.2543x; 1.1765x over previous
//
#include <hip/hip_runtime.h>
#include <math.h>

#define TT 2048
#define BB 32
#define EE 512
#define NN 512

typedef short bf16x8 __attribute__((ext_vector_type(8)));
typedef float f32x4 __attribute__((ext_vector_type(4)));

__device__ __forceinline__ short bf16_rne(float x) {
    const unsigned u = __float_as_uint(x);
    return (short)((u + 0x7FFFu + ((u >> 16) & 1u)) >> 16);
}
__device__ __forceinline__ float bf16_f32(short h) {
    return __uint_as_float(((unsigned)(unsigned short)h) << 16);
}
__device__ __forceinline__ void gload_lds16(const void* g, void* l) {
    __builtin_amdgcn_global_load_lds((const __attribute__((address_space(1))) void*)g,
                                     (__attribute__((address_space(3))) void*)l, 16, 0, 0);
}

// ---------------------------------------------------------------------------
// padding_mask dtype detector: int32 0/1 words stay <=1; byte-bool rows are
// monotonic so any packed word is 0x01000000/0x01010000/0x01010101/... (>1).
__global__ void detect_mask_kernel(const unsigned* __restrict__ pm, int* __restrict__ flag) {
    __shared__ int s[1024];
    const int l = threadIdx.x;
    int bad = 0;
    for (int i = l; i < BB * TT; i += 1024) bad |= (pm[i] > 1u);
    s[l] = bad;
    __syncthreads();
    for (int st = 512; st > 0; st >>= 1) { if (l < st) s[l] |= s[l + st]; __syncthreads(); }
    if (l == 0) *flag = s[0];
}

__device__ __forceinline__ int pad_at(const void* pm, int idx, int isByte) {
    return isByte ? (int)(((const unsigned char*)pm)[idx] != 0)
                  : (int)(((const int*)pm)[idx] != 0);
}

// ---------------------------------------------------------------------------
// padding_start[b] = count of not-pad = lengths[b]
__global__ void compute_ps_kernel(const void* __restrict__ pm, const int* __restrict__ flag,
                                  int* __restrict__ ps) {
    __shared__ int s[256];
    const int b = blockIdx.x, l = threadIdx.x;
    const int isByte = *flag;
    int cnt = 0;
    for (int t = l; t < TT; t += 256) cnt += (pad_at(pm, b * TT + t, isByte) == 0);
    s[l] = cnt;
    __syncthreads();
    for (int st = 128; st > 0; st >>= 1) { if (l < st) s[l] += s[l + st]; __syncthreads(); }
    if (l == 0) ps[b] = s[0];
}

// ---------------------------------------------------------------------------
// One-time W split+transpose: W[E][N] fp32 -> Wh/Wl[N][E] bf16 (k contiguous),
// RNE hi + RNE residual lo. Scratch lives in out_cif (overwritten later).
__global__ __launch_bounds__(256) void split_w_kernel(const float* __restrict__ W,
                                                      short* __restrict__ Wh,
                                                      short* __restrict__ Wl) {
    __shared__ float tile[32][33];
    const int bn = blockIdx.x, bk = blockIdx.y;
    const int tx = threadIdx.x & 31, ty = threadIdx.x >> 5;
    for (int i = ty; i < 32; i += 8)
        tile[i][tx] = W[(size_t)(bk * 32 + i) * NN + bn * 32 + tx];
    __syncthreads();
    for (int i = ty; i < 32; i += 8) {
        const float val = tile[tx][i];
        const short h = bf16_rne(val);
        const short lo = bf16_rne(val - bf16_f32(h));
        const size_t o = (size_t)(bn * 32 + i) * EE + bk * 32 + tx;
        Wh[o] = h;
        Wl[o] = lo;
    }
}

// ---------------------------------------------------------------------------
// MFMA GEMM + fused relu/dot(v)/sigmoid/mask.  (unchanged, passed r2/r3)
__global__ __launch_bounds__(256, 2) void gemm_weight_mfma(
    const float* __restrict__ x, const void* __restrict__ pm, const int* __restrict__ flag,
    const short* __restrict__ Wh, const short* __restrict__ Wl,
    const float* __restrict__ bias, const float* __restrict__ v, const float* __restrict__ vb,
    float* __restrict__ weight_bt) {
    __shared__ __align__(16) short Ah[128 * 64];
    __shared__ __align__(16) short Al[128 * 64];
    __shared__ __align__(16) short Bh[128 * 64];
    __shared__ __align__(16) short Bl[128 * 64];
    __shared__ float bias_s[512], v_s[512];
    __shared__ float lsum[128][2];

    const int tid = threadIdx.x;
    const int l = tid & 63, wid = tid >> 6;
    const int wr = wid >> 1, wc = wid & 1;
    const int q = l >> 4, li = l & 15, x7 = l & 7;
    const int tp = blockIdx.x;

    for (int i = tid; i < 512; i += 256) { bias_s[i] = bias[i]; v_s[i] = v[i]; }

    const float* xblk = x + (size_t)tp * 128 * EE;
    const int arow = tid >> 1;
    const int akoff = (tid & 1) * 32;
    const int ac0 = akoff >> 3;
    const int aswz = arow & 7;

    float rowsum[4][4];
#pragma unroll
    for (int m = 0; m < 4; ++m)
#pragma unroll
        for (int r = 0; r < 4; ++r) rowsum[m][r] = 0.f;

    for (int nc = 0; nc < 4; ++nc) {
        const int n0 = nc * 128;
        f32x4 acc[4][4];
#pragma unroll
        for (int m = 0; m < 4; ++m)
#pragma unroll
            for (int n = 0; n < 4; ++n) acc[m][n] = (f32x4){0.f, 0.f, 0.f, 0.f};

        for (int k0 = 0; k0 < EE; k0 += 64) {
            __syncthreads();
#pragma unroll
            for (int i = 0; i < 4; ++i) {
                const int u = i * 256 + tid;
                const int row = u >> 3, c = u & 7;
                const int ge = (n0 + row) * EE + k0 + ((c ^ (row & 7)) << 3);
                gload_lds16(Wh + ge, &Bh[u * 8]);
                gload_lds16(Wl + ge, &Bl[u * 8]);
            }
            const float* xr = xblk + (size_t)arow * EE + k0 + akoff;
#pragma unroll
            for (int g = 0; g < 4; ++g) {
                float e[8];
                *(float4*)&e[0] = *(const float4*)&xr[g * 8];
                *(float4*)&e[4] = *(const float4*)&xr[g * 8 + 4];
                bf16x8 hv, lv;
#pragma unroll
                for (int j = 0; j < 8; ++j) {
                    const short h = bf16_rne(e[j]);
                    hv[j] = h;
                    lv[j] = bf16_rne(e[j] - bf16_f32(h));
                }
                const int p = arow * 64 + (((ac0 + g) ^ aswz) << 3);
                *(bf16x8*)&Ah[p] = hv;
                *(bf16x8*)&Al[p] = lv;
            }
            __syncthreads();
#pragma unroll
            for (int kf = 0; kf < 2; ++kf) {
                const int co = (((kf << 2) + q) ^ x7) << 3;
                bf16x8 ah[4], al[4];
#pragma unroll
                for (int m = 0; m < 4; ++m) {
                    const int ro = (wr * 64 + m * 16 + li) * 64 + co;
                    ah[m] = *(const bf16x8*)&Ah[ro];
                    al[m] = *(const bf16x8*)&Al[ro];
                }
#pragma unroll
                for (int n = 0; n < 4; ++n) {
                    const int bo = (wc * 64 + n * 16 + li) * 64 + co;
                    const bf16x8 bh = *(const bf16x8*)&Bh[bo];
                    const bf16x8 bl = *(const bf16x8*)&Bl[bo];
#pragma unroll
                    for (int m = 0; m < 4; ++m) {
                        acc[m][n] = __builtin_amdgcn_mfma_f32_16x16x32_bf16(ah[m], bh, acc[m][n], 0, 0, 0);
                        acc[m][n] = __builtin_amdgcn_mfma_f32_16x16x32_bf16(al[m], bh, acc[m][n], 0, 0, 0);
                        acc[m][n] = __builtin_amdgcn_mfma_f32_16x16x32_bf16(ah[m], bl, acc[m][n], 0, 0, 0);
                    }
                }
            }
        }
#pragma unroll
        for (int m = 0; m < 4; ++m)
#pragma unroll
            for (int n = 0; n < 4; ++n) {
                const int col = n0 + wc * 64 + n * 16 + li;
                const float bcol = bias_s[col], vcol = v_s[col];
#pragma unroll
                for (int r = 0; r < 4; ++r) {
                    const float h = fmaxf(acc[m][n][r] + bcol, 0.f);
                    rowsum[m][r] = fmaf(h, vcol, rowsum[m][r]);
                }
            }
    }
#pragma unroll
    for (int m = 0; m < 4; ++m)
#pragma unroll
        for (int r = 0; r < 4; ++r) {
            float s = rowsum[m][r];
            s += __shfl_xor(s, 1, 64);
            s += __shfl_xor(s, 2, 64);
            s += __shfl_xor(s, 4, 64);
            s += __shfl_xor(s, 8, 64);
            rowsum[m][r] = s;
        }
    if (li == 0) {
#pragma unroll
        for (int m = 0; m < 4; ++m)
#pragma unroll
            for (int r = 0; r < 4; ++r)
                lsum[wr * 64 + m * 16 + q * 4 + r][wc] = rowsum[m][r];
    }
    __syncthreads();
    if (tid < 128) {
        const int isByte = *flag;
        const float logit = lsum[tid][0] + lsum[tid][1] + *vb;
        const float wg = 1.0f / (1.0f + expf(-logit));
        const int gr = tp * 128 + tid;
        const int t = gr >> 5, b = gr & 31;
        weight_bt[(size_t)b * TT + t] = pad_at(pm, b * TT + t, isByte) ? 0.f : wg;
    }
}

// ---------------------------------------------------------------------------
// Scan v3: minimal serial core + parallel derivation.
// Lane 0 runs ONLY the 5-op branchless recurrence (bit-exact to reference
// rounding on both paths), storing c_t to LDS: a=1-c; s=c+w; b=w-a;
// c = s>=1 ? b : s.  Everything else (fired bits, cc, marks, recs, tail,
// qsum) is a pure function of cseq[] + wsm[] and is derived by all 64 lanes
// in parallel. Near-threshold fire decisions (|cseq[t-1]+w-1| < BAND) are
// detected in parallel; each event triggers a cooperative fp32 recompute of
// that weight and a re-run of the cheap serial core.
#define BAND 2.5e-4f
__global__ __launch_bounds__(64) void cif_scan_kernel(
    const float* __restrict__ weight_bt, const int* __restrict__ ps_arr,
    const float* __restrict__ x, const float* __restrict__ W,
    const float* __restrict__ bias, const float* __restrict__ v,
    const float* __restrict__ vb,
    float* __restrict__ cc_bt, float4* __restrict__ recs,
    int* __restrict__ nfr, float* __restrict__ out_q, float* __restrict__ out_marks) {
    __shared__ __align__(16) float wsm[TT];
    __shared__ __align__(16) float cseq[TT];
    __shared__ __align__(16) float xrow[EE];
    const int b = blockIdx.x, l = threadIdx.x;
    const int ps = ps_arr[b];
    const float* wrow = weight_bt + (size_t)b * TT;

    // stage full weight row (8 KB): 64 lanes x 32 floats, coalesced
    for (int t = l * 8; t < TT; t += 64 * 8) {
        *(float4*)&wsm[t]     = *(const float4*)&wrow[t];
        *(float4*)&wsm[t + 4] = *(const float4*)&wrow[t + 4];
    }
    __syncthreads();

    int last_fixed = -1;
    for (;;) {
        if (l == 0) {
            // minimal serial recurrence: ~14 dependent cycles per step
            float c = 0.f;
            float4 na = *(const float4*)&wsm[0];
            float4 nb = *(const float4*)&wsm[4];
            for (int t = 0; t < TT; t += 8) {
                const float4 wa = na, wb = nb;
                const int tn = (t + 8) & (TT - 1);     // preload next group
                na = *(const float4*)&wsm[tn];
                nb = *(const float4*)&wsm[tn + 4];
                const float wv[8] = {wa.x, wa.y, wa.z, wa.w, wb.x, wb.y, wb.z, wb.w};
                float cs[8];
#pragma unroll
                for (int u = 0; u < 8; ++u) {
                    const float w = wv[u];
                    const float a = 1.0f - c;
                    const float s = c + w;
                    const float bb = w - a;
                    c = (s >= 1.0f) ? bb : s;          // v_cmp + v_cndmask
                    cs[u] = c;
                }
                *(float4*)&cseq[t]     = make_float4(cs[0], cs[1], cs[2], cs[3]);
                *(float4*)&cseq[t + 4] = make_float4(cs[4], cs[5], cs[6], cs[7]);
            }
        }
        __syncthreads();
        // parallel: earliest near-threshold step not yet fixed
        int myEv = 0x7fffffff;
        for (int t = l; t < TT; t += 64) {
            const float w = wsm[t];
            if (w > 0.f && t > last_fixed && myEv == 0x7fffffff) {
                const float cprev = t ? cseq[t - 1] : 0.f;
                if (fabsf(cprev + w - 1.0f) < BAND) myEv = t;
            }
        }
#pragma unroll
        for (int s = 32; s >= 1; s >>= 1) myEv = min(myEv, __shfl_xor(myEv, s, 64));
        if (myEv == 0x7fffffff) break;
        const int ev = myEv;
        // cooperative full-fp32 recompute of weight(b, ev), 64 lanes
        {
            const float* xr = &x[((size_t)ev * BB + b) * EE];
            *(float4*)&xrow[l * 8]     = *(const float4*)&xr[l * 8];
            *(float4*)&xrow[l * 8 + 4] = *(const float4*)&xr[l * 8 + 4];
            __syncthreads();
            float part = 0.f;
            for (int jj = 0; jj < 8; ++jj) {
                const int j = jj * 64 + l;             // coalesced W reads per e
                float h = bias[j];
                for (int e = 0; e < EE; ++e) h = fmaf(xrow[e], W[(size_t)e * NN + j], h);
                part = fmaf(fmaxf(h, 0.f), v[j], part);
            }
#pragma unroll
            for (int s = 32; s >= 1; s >>= 1) part += __shfl_xor(part, s, 64);
            if (l == 0) wsm[ev] = 1.0f / (1.0f + expf(-(part + *vb)));
            last_fixed = ev;                           // uniform across lanes
            __syncthreads();
        }
    }

    // ---- parallel derivation (weights + cseq now clean) ----
    // P1: per-lane contiguous 32-step range -> fired bitmask
    const int base = l * 32;
    unsigned fmask = 0u;
    for (int u = 0; u < 32; ++u) {
        const int t = base + u;
        const float cprev = t ? cseq[t - 1] : 0.f;
        if (cprev + wsm[t] >= 1.0f) fmask |= (1u << u);   // bit-exact same add
    }
    const int myF = __popc(fmask);
    int myLast = fmask ? (base + (31 - __clz(fmask))) : -1;

    // P2: wave scans (inclusive sum of fires; exclusive max of last-fire idx)
    int inc = myF;
#pragma unroll
    for (int off = 1; off < 64; off <<= 1) {
        const int n = __shfl_up(inc, off, 64);
        if (l >= off) inc += n;
    }
    const int exF = inc - myF;
    const int totF = __shfl(inc, 63, 64);
    int incLast = myLast;
#pragma unroll
    for (int off = 1; off < 64; off <<= 1) {
        const int n = __shfl_up(incLast, off, 64);
        if (l >= off) incLast = (incLast > n) ? incLast : n;
    }
    int prevFire = __shfl_up(incLast, 1, 64);
    if (l == 0) prevFire = -1;
    int tf = (prevFire > 0) ? prevFire : 0;   // t_first for my range (0 if none)

    // P3: emit fire recs (slot = global fire rank); capture tail rec at t==ps.
    // fc = cseq[tf]: for fire-start segments cseq[tf] = w - remained; for the
    // initial segment tf=0, cseq[0] = w_0. Matches serial fc exactly.
    int slot = exF;
    int tailWrote = 0;
    for (int u = 0; u < 32; ++u) {
        const int t = base + u;
        if (fmask & (1u << u)) {
            recs[(size_t)b * TT + slot] =
                make_float4(__int_as_float(tf), __int_as_float(t), cseq[tf], 1.0f);
            ++slot;
            tf = t;
        }
        if (t == ps) {
            const float cw = cseq[t];
            if (cw > 0.6f && totF < TT) {
                recs[(size_t)b * TT + totF] =
                    make_float4(__int_as_float(tf), __int_as_float(t - 1), cseq[tf],
                                1.0f / (cw + 1e-10f));
                tailWrote = 1;
            }
        }
    }
    const int tailAny = (__ballot(tailWrote) != 0ull) ? 1 : 0;

    // P4: coalesced cc / marks / qsum
    float qpart = 0.f;
    for (int t = l; t < TT; t += 64) {
        const float w = wsm[t];
        const float cprev = t ? cseq[t - 1] : 0.f;
        const bool fired = (cprev + w) >= 1.0f;
        const float cc = fired ? (1.0f - cprev) : w;
        const bool tail = (t == ps) && (cseq[t] > 0.6f);
        cc_bt[(size_t)b * TT + t] = cc;
        out_marks[(size_t)b * TT + t] = (fired || tail) ? 1.f : 0.f;
        qpart += w;
    }
#pragma unroll
    for (int s = 32; s >= 1; s >>= 1) qpart += __shfl_xor(qpart, s, 64);
    if (l == 0) { out_q[b] = qpart; nfr[b] = totF + tailAny; }
}

// ---------------------------------------------------------------------------
// Parallel frame materialization: block (j, b) -> compacted slot j of batch b.
__global__ __launch_bounds__(128) void cif_out_kernel(
    const float* __restrict__ x, const float* __restrict__ cc_bt,
    const float4* __restrict__ recs, const int* __restrict__ nfr,
    float* __restrict__ out_cif, float* __restrict__ out_mask) {
    const int j = blockIdx.x, b = blockIdx.y;
    const int l = threadIdx.x;
    const int m = nfr[b];
    float4 acc = make_float4(0.f, 0.f, 0.f, 0.f);
    const size_t obase = ((size_t)b * TT + j) * EE + l * 4;
    if (j < m) {
        const float4 r = recs[b * TT + j];
        const int t0 = __float_as_int(r.x);
        const int t1 = __float_as_int(r.y);
        const float fcoef = r.z, scale = r.w;
        for (int t = t0; t <= t1; ++t) {
            const float coeff = (t == t0) ? fcoef : cc_bt[(size_t)b * TT + t];
            const float4 xv = *(const float4*)&x[((size_t)t * BB + b) * EE + l * 4];
            acc.x = fmaf(coeff, xv.x, acc.x);
            acc.y = fmaf(coeff, xv.y, acc.y);
            acc.z = fmaf(coeff, xv.z, acc.z);
            acc.w = fmaf(coeff, xv.w, acc.w);
        }
        acc.x *= scale; acc.y *= scale; acc.z *= scale; acc.w *= scale;
        if (l == 0) out_mask[b * TT + j] = 1.f;
    } else {
        if (l == 0) out_mask[b * TT + j] = 0.f;
    }
    *(float4*)&out_cif[obase] = acc;
}

// ---------------------------------------------------------------------------
extern "C" void kernel_launch(void* const* d_in, const int* in_sizes, int n_in,
                              void* d_out, int out_size, void* d_ws, size_t ws_size,
                              hipStream_t stream) {
    const float* x    = (const float*)d_in[0];   // (T, B, E)
    const void*  pm   = d_in[1];                 // (B, T) bool -> int32 or bytes (detected)
    const float* W    = (const float*)d_in[2];   // (E, N)
    const float* bias = (const float*)d_in[3];   // (N,)
    const float* v    = (const float*)d_in[4];   // (N, 1)
    const float* vb   = (const float*)d_in[5];   // (1,)

    // workspace: same footprint class as the proven round-0 kernel (~1.5 MB)
    float* ws        = (float*)d_ws;
    float* weight_bt = ws;                                 // BB*TT
    float* cc_bt     = ws + (size_t)TT * BB;               // BB*TT
    float4* recs     = (float4*)(ws + 2 * (size_t)TT * BB);// BB*TT float4
    int* nfr         = (int*)(ws + 2 * (size_t)TT * BB + 4 * (size_t)BB * TT);
    int* ps          = nfr + BB;
    int* flag        = ps + BB;

    float* out_cif   = (float*)d_out;                     // (B, T, E)
    float* out_mask  = out_cif + (size_t)BB * TT * EE;    // (B, T)
    float* out_q     = out_mask + (size_t)BB * TT;        // (B,)
    float* out_marks = out_q + BB;                        // (B, T)

    // W-split scratch lives in out_cif (1 MB of 128 MB); gemm consumes it
    // before cif_out_kernel overwrites every byte of out_cif (stream-ordered).
    short* Whs = (short*)out_cif;                         // 512 KB
    short* Wls = Whs + (size_t)NN * EE;                   // 512 KB

    detect_mask_kernel<<<1, 1024, 0, stream>>>((const unsigned*)pm, flag);
    compute_ps_kernel<<<BB, 256, 0, stream>>>(pm, flag, ps);
    split_w_kernel<<<dim3(16, 16), 256, 0, stream>>>(W, Whs, Wls);
    gemm_weight_mfma<<<512, 256, 0, stream>>>(x, pm, flag, Whs, Wls, bias, v, vb, weight_bt);
    cif_scan_kernel<<<BB, 64, 0, stream>>>(weight_bt, ps, x, W, bias, v, vb,
                                           cc_bt, recs, nfr, out_q, out_marks);
    cif_out_kernel<<<dim3(TT, BB), 128, 0, stream>>>(x, cc_bt, recs, nfr, out_cif, out_mask);
}

// Round 5
// 642.553 us; speedup vs baseline: 1.4676x; 1.1700x over previous
//
#include <hip/hip_runtime.h>
#include <math.h>

#define TT 2048
#define BB 32
#define EE 512
#define NN 512

typedef short bf16x8 __attribute__((ext_vector_type(8)));
typedef float f32x4 __attribute__((ext_vector_type(4)));

__device__ __forceinline__ short bf16_rne(float x) {
    const unsigned u = __float_as_uint(x);
    return (short)((u + 0x7FFFu + ((u >> 16) & 1u)) >> 16);
}
__device__ __forceinline__ float bf16_f32(short h) {
    return __uint_as_float(((unsigned)(unsigned short)h) << 16);
}
__device__ __forceinline__ void gload_lds16(const void* g, void* l) {
    __builtin_amdgcn_global_load_lds((const __attribute__((address_space(1))) void*)g,
                                     (__attribute__((address_space(3))) void*)l, 16, 0, 0);
}

// ---------------------------------------------------------------------------
// padding_mask dtype detector: int32 0/1 words stay <=1; byte-bool rows are
// monotonic so any packed word is 0x01000000/0x01010000/0x01010101/... (>1).
__global__ void detect_mask_kernel(const unsigned* __restrict__ pm, int* __restrict__ flag) {
    __shared__ int s[1024];
    const int l = threadIdx.x;
    int bad = 0;
    for (int i = l; i < BB * TT; i += 1024) bad |= (pm[i] > 1u);
    s[l] = bad;
    __syncthreads();
    for (int st = 512; st > 0; st >>= 1) { if (l < st) s[l] |= s[l + st]; __syncthreads(); }
    if (l == 0) *flag = s[0];
}

__device__ __forceinline__ int pad_at(const void* pm, int idx, int isByte) {
    return isByte ? (int)(((const unsigned char*)pm)[idx] != 0)
                  : (int)(((const int*)pm)[idx] != 0);
}

// ---------------------------------------------------------------------------
// padding_start[b] = count of not-pad = lengths[b]
__global__ void compute_ps_kernel(const void* __restrict__ pm, const int* __restrict__ flag,
                                  int* __restrict__ ps) {
    __shared__ int s[256];
    const int b = blockIdx.x, l = threadIdx.x;
    const int isByte = *flag;
    int cnt = 0;
    for (int t = l; t < TT; t += 256) cnt += (pad_at(pm, b * TT + t, isByte) == 0);
    s[l] = cnt;
    __syncthreads();
    for (int st = 128; st > 0; st >>= 1) { if (l < st) s[l] += s[l + st]; __syncthreads(); }
    if (l == 0) ps[b] = s[0];
}

// ---------------------------------------------------------------------------
// One-time W split+transpose: W[E][N] fp32 -> Wh/Wl[N][E] bf16 (k contiguous),
// RNE hi + RNE residual lo. Scratch lives in out_cif (overwritten later).
__global__ __launch_bounds__(256) void split_w_kernel(const float* __restrict__ W,
                                                      short* __restrict__ Wh,
                                                      short* __restrict__ Wl) {
    __shared__ float tile[32][33];
    const int bn = blockIdx.x, bk = blockIdx.y;
    const int tx = threadIdx.x & 31, ty = threadIdx.x >> 5;
    for (int i = ty; i < 32; i += 8)
        tile[i][tx] = W[(size_t)(bk * 32 + i) * NN + bn * 32 + tx];
    __syncthreads();
    for (int i = ty; i < 32; i += 8) {
        const float val = tile[tx][i];
        const short h = bf16_rne(val);
        const short lo = bf16_rne(val - bf16_f32(h));
        const size_t o = (size_t)(bn * 32 + i) * EE + bk * 32 + tx;
        Wh[o] = h;
        Wl[o] = lo;
    }
}

// ---------------------------------------------------------------------------
// MFMA GEMM + fused relu/dot(v)/sigmoid/mask.  (unchanged, passed r2/r3/r4)
__global__ __launch_bounds__(256, 2) void gemm_weight_mfma(
    const float* __restrict__ x, const void* __restrict__ pm, const int* __restrict__ flag,
    const short* __restrict__ Wh, const short* __restrict__ Wl,
    const float* __restrict__ bias, const float* __restrict__ v, const float* __restrict__ vb,
    float* __restrict__ weight_bt) {
    __shared__ __align__(16) short Ah[128 * 64];
    __shared__ __align__(16) short Al[128 * 64];
    __shared__ __align__(16) short Bh[128 * 64];
    __shared__ __align__(16) short Bl[128 * 64];
    __shared__ float bias_s[512], v_s[512];
    __shared__ float lsum[128][2];

    const int tid = threadIdx.x;
    const int l = tid & 63, wid = tid >> 6;
    const int wr = wid >> 1, wc = wid & 1;
    const int q = l >> 4, li = l & 15, x7 = l & 7;
    const int tp = blockIdx.x;

    for (int i = tid; i < 512; i += 256) { bias_s[i] = bias[i]; v_s[i] = v[i]; }

    const float* xblk = x + (size_t)tp * 128 * EE;
    const int arow = tid >> 1;
    const int akoff = (tid & 1) * 32;
    const int ac0 = akoff >> 3;
    const int aswz = arow & 7;

    float rowsum[4][4];
#pragma unroll
    for (int m = 0; m < 4; ++m)
#pragma unroll
        for (int r = 0; r < 4; ++r) rowsum[m][r] = 0.f;

    for (int nc = 0; nc < 4; ++nc) {
        const int n0 = nc * 128;
        f32x4 acc[4][4];
#pragma unroll
        for (int m = 0; m < 4; ++m)
#pragma unroll
            for (int n = 0; n < 4; ++n) acc[m][n] = (f32x4){0.f, 0.f, 0.f, 0.f};

        for (int k0 = 0; k0 < EE; k0 += 64) {
            __syncthreads();
#pragma unroll
            for (int i = 0; i < 4; ++i) {
                const int u = i * 256 + tid;
                const int row = u >> 3, c = u & 7;
                const int ge = (n0 + row) * EE + k0 + ((c ^ (row & 7)) << 3);
                gload_lds16(Wh + ge, &Bh[u * 8]);
                gload_lds16(Wl + ge, &Bl[u * 8]);
            }
            const float* xr = xblk + (size_t)arow * EE + k0 + akoff;
#pragma unroll
            for (int g = 0; g < 4; ++g) {
                float e[8];
                *(float4*)&e[0] = *(const float4*)&xr[g * 8];
                *(float4*)&e[4] = *(const float4*)&xr[g * 8 + 4];
                bf16x8 hv, lv;
#pragma unroll
                for (int j = 0; j < 8; ++j) {
                    const short h = bf16_rne(e[j]);
                    hv[j] = h;
                    lv[j] = bf16_rne(e[j] - bf16_f32(h));
                }
                const int p = arow * 64 + (((ac0 + g) ^ aswz) << 3);
                *(bf16x8*)&Ah[p] = hv;
                *(bf16x8*)&Al[p] = lv;
            }
            __syncthreads();
#pragma unroll
            for (int kf = 0; kf < 2; ++kf) {
                const int co = (((kf << 2) + q) ^ x7) << 3;
                bf16x8 ah[4], al[4];
#pragma unroll
                for (int m = 0; m < 4; ++m) {
                    const int ro = (wr * 64 + m * 16 + li) * 64 + co;
                    ah[m] = *(const bf16x8*)&Ah[ro];
                    al[m] = *(const bf16x8*)&Al[ro];
                }
#pragma unroll
                for (int n = 0; n < 4; ++n) {
                    const int bo = (wc * 64 + n * 16 + li) * 64 + co;
                    const bf16x8 bh = *(const bf16x8*)&Bh[bo];
                    const bf16x8 bl = *(const bf16x8*)&Bl[bo];
#pragma unroll
                    for (int m = 0; m < 4; ++m) {
                        acc[m][n] = __builtin_amdgcn_mfma_f32_16x16x32_bf16(ah[m], bh, acc[m][n], 0, 0, 0);
                        acc[m][n] = __builtin_amdgcn_mfma_f32_16x16x32_bf16(al[m], bh, acc[m][n], 0, 0, 0);
                        acc[m][n] = __builtin_amdgcn_mfma_f32_16x16x32_bf16(ah[m], bl, acc[m][n], 0, 0, 0);
                    }
                }
            }
        }
#pragma unroll
        for (int m = 0; m < 4; ++m)
#pragma unroll
            for (int n = 0; n < 4; ++n) {
                const int col = n0 + wc * 64 + n * 16 + li;
                const float bcol = bias_s[col], vcol = v_s[col];
#pragma unroll
                for (int r = 0; r < 4; ++r) {
                    const float h = fmaxf(acc[m][n][r] + bcol, 0.f);
                    rowsum[m][r] = fmaf(h, vcol, rowsum[m][r]);
                }
            }
    }
#pragma unroll
    for (int m = 0; m < 4; ++m)
#pragma unroll
        for (int r = 0; r < 4; ++r) {
            float s = rowsum[m][r];
            s += __shfl_xor(s, 1, 64);
            s += __shfl_xor(s, 2, 64);
            s += __shfl_xor(s, 4, 64);
            s += __shfl_xor(s, 8, 64);
            rowsum[m][r] = s;
        }
    if (li == 0) {
#pragma unroll
        for (int m = 0; m < 4; ++m)
#pragma unroll
            for (int r = 0; r < 4; ++r)
                lsum[wr * 64 + m * 16 + q * 4 + r][wc] = rowsum[m][r];
    }
    __syncthreads();
    if (tid < 128) {
        const int isByte = *flag;
        const float logit = lsum[tid][0] + lsum[tid][1] + *vb;
        const float wg = 1.0f / (1.0f + expf(-logit));
        const int gr = tp * 128 + tid;
        const int t = gr >> 5, b = gr & 31;
        weight_bt[(size_t)b * TT + t] = pad_at(pm, b * TT + t, isByte) ? 0.f : wg;
    }
}

// ---------------------------------------------------------------------------
// Scan v4: minimal serial core + parallel derivation (structure = round 4,
// which passed). Changes: (1) BAND 2.5e-4 -> 5e-5 (bf16-split fire-margin
// error is ~4e-6 sigma; 5e-5 is ~12 sigma; cuts rescue events ~5x);
// (2) rescue recompute uses 4 independent accumulators so the 4096 L2 loads
// pipeline instead of serializing behind a dependent fmaf chain (was ~130us
// per event -> ~15us); (3) serial core gets depth-2 LDS prefetch and the
// post-fix re-pass restarts at the fixed step's group (cseq before it is
// unchanged by construction).
#define BAND 5e-5f
__global__ __launch_bounds__(64) void cif_scan_kernel(
    const float* __restrict__ weight_bt, const int* __restrict__ ps_arr,
    const float* __restrict__ x, const float* __restrict__ W,
    const float* __restrict__ bias, const float* __restrict__ v,
    const float* __restrict__ vb,
    float* __restrict__ cc_bt, float4* __restrict__ recs,
    int* __restrict__ nfr, float* __restrict__ out_q, float* __restrict__ out_marks) {
    __shared__ __align__(16) float wsm[TT];
    __shared__ __align__(16) float cseq[TT];
    __shared__ __align__(16) float xrow[EE];
    const int b = blockIdx.x, l = threadIdx.x;
    const int ps = ps_arr[b];
    const float* wrow = weight_bt + (size_t)b * TT;

    // stage full weight row (8 KB): 64 lanes x 32 floats, coalesced
    for (int t = l * 8; t < TT; t += 64 * 8) {
        *(float4*)&wsm[t]     = *(const float4*)&wrow[t];
        *(float4*)&wsm[t + 4] = *(const float4*)&wrow[t + 4];
    }
    __syncthreads();

    int last_fixed = -1;
    int t0s = 0;                     // group-aligned serial-core start
    for (;;) {
        if (l == 0) {
            // minimal branchless serial recurrence, depth-2 LDS prefetch
            float c = (t0s > 0) ? cseq[t0s - 1] : 0.f;
            float4 n1a = *(const float4*)&wsm[t0s];
            float4 n1b = *(const float4*)&wsm[t0s + 4];
            const int tp8 = (t0s + 8) & (TT - 1);
            float4 n2a = *(const float4*)&wsm[tp8];
            float4 n2b = *(const float4*)&wsm[tp8 + 4];
            for (int t = t0s; t < TT; t += 8) {
                const float4 wa = n1a, wb = n1b;
                n1a = n2a; n1b = n2b;
                const int tn = (t + 16) & (TT - 1);   // depth-2 preload
                n2a = *(const float4*)&wsm[tn];
                n2b = *(const float4*)&wsm[tn + 4];
                const float wv[8] = {wa.x, wa.y, wa.z, wa.w, wb.x, wb.y, wb.z, wb.w};
                float cs[8];
#pragma unroll
                for (int u = 0; u < 8; ++u) {
                    const float w = wv[u];
                    const float a = 1.0f - c;
                    const float s = c + w;
                    const float bb = w - a;
                    c = (s >= 1.0f) ? bb : s;          // v_cmp + v_cndmask
                    cs[u] = c;
                }
                *(float4*)&cseq[t]     = make_float4(cs[0], cs[1], cs[2], cs[3]);
                *(float4*)&cseq[t + 4] = make_float4(cs[4], cs[5], cs[6], cs[7]);
            }
        }
        __syncthreads();
        // parallel: earliest near-threshold step not yet fixed
        int myEv = 0x7fffffff;
        for (int t = l; t < TT; t += 64) {
            const float w = wsm[t];
            if (w > 0.f && t > last_fixed && myEv == 0x7fffffff) {
                const float cprev = t ? cseq[t - 1] : 0.f;
                if (fabsf(cprev + w - 1.0f) < BAND) myEv = t;
            }
        }
#pragma unroll
        for (int s = 32; s >= 1; s >>= 1) myEv = min(myEv, __shfl_xor(myEv, s, 64));
        if (myEv == 0x7fffffff) break;
        const int ev = myEv;
        // cooperative full-fp32 recompute of weight(b, ev), 64 lanes.
        // 4 independent accumulators -> global W loads pipeline (not chained).
        {
            const float* xr = &x[((size_t)ev * BB + b) * EE];
            *(float4*)&xrow[l * 8]     = *(const float4*)&xr[l * 8];
            *(float4*)&xrow[l * 8 + 4] = *(const float4*)&xr[l * 8 + 4];
            __syncthreads();
            float part = 0.f;
            for (int jj = 0; jj < 8; ++jj) {
                const int j = jj * 64 + l;             // coalesced W reads per e
                float h0 = 0.f, h1 = 0.f, h2 = 0.f, h3 = 0.f;
#pragma unroll 4
                for (int e = 0; e < EE; e += 4) {
                    h0 = fmaf(xrow[e + 0], W[(size_t)(e + 0) * NN + j], h0);
                    h1 = fmaf(xrow[e + 1], W[(size_t)(e + 1) * NN + j], h1);
                    h2 = fmaf(xrow[e + 2], W[(size_t)(e + 2) * NN + j], h2);
                    h3 = fmaf(xrow[e + 3], W[(size_t)(e + 3) * NN + j], h3);
                }
                const float h = bias[j] + ((h0 + h1) + (h2 + h3));
                part = fmaf(fmaxf(h, 0.f), v[j], part);
            }
#pragma unroll
            for (int s = 32; s >= 1; s >>= 1) part += __shfl_xor(part, s, 64);
            if (l == 0) wsm[ev] = 1.0f / (1.0f + expf(-(part + *vb)));
            last_fixed = ev;                           // uniform across lanes
            t0s = ev & ~7;                             // re-pass from ev's group
            __syncthreads();
        }
    }

    // ---- parallel derivation (weights + cseq now clean) ----
    // P1: per-lane contiguous 32-step range -> fired bitmask
    const int base = l * 32;
    unsigned fmask = 0u;
    for (int u = 0; u < 32; ++u) {
        const int t = base + u;
        const float cprev = t ? cseq[t - 1] : 0.f;
        if (cprev + wsm[t] >= 1.0f) fmask |= (1u << u);   // bit-exact same add
    }
    const int myF = __popc(fmask);
    int myLast = fmask ? (base + (31 - __clz(fmask))) : -1;

    // P2: wave scans (inclusive sum of fires; exclusive max of last-fire idx)
    int inc = myF;
#pragma unroll
    for (int off = 1; off < 64; off <<= 1) {
        const int n = __shfl_up(inc, off, 64);
        if (l >= off) inc += n;
    }
    const int exF = inc - myF;
    const int totF = __shfl(inc, 63, 64);
    int incLast = myLast;
#pragma unroll
    for (int off = 1; off < 64; off <<= 1) {
        const int n = __shfl_up(incLast, off, 64);
        if (l >= off) incLast = (incLast > n) ? incLast : n;
    }
    int prevFire = __shfl_up(incLast, 1, 64);
    if (l == 0) prevFire = -1;
    int tf = (prevFire > 0) ? prevFire : 0;   // t_first for my range (0 if none)

    // P3: emit fire recs (slot = global fire rank); capture tail rec at t==ps.
    // fc = cseq[tf]: for fire-start segments cseq[tf] = w - remained; for the
    // initial segment tf=0, cseq[0] = w_0. Matches serial fc exactly.
    int slot = exF;
    int tailWrote = 0;
    for (int u = 0; u < 32; ++u) {
        const int t = base + u;
        if (fmask & (1u << u)) {
            recs[(size_t)b * TT + slot] =
                make_float4(__int_as_float(tf), __int_as_float(t), cseq[tf], 1.0f);
            ++slot;
            tf = t;
        }
        if (t == ps) {
            const float cw = cseq[t];
            if (cw > 0.6f && totF < TT) {
                recs[(size_t)b * TT + totF] =
                    make_float4(__int_as_float(tf), __int_as_float(t - 1), cseq[tf],
                                1.0f / (cw + 1e-10f));
                tailWrote = 1;
            }
        }
    }
    const int tailAny = (__ballot(tailWrote) != 0ull) ? 1 : 0;

    // P4: coalesced cc / marks / qsum
    float qpart = 0.f;
    for (int t = l; t < TT; t += 64) {
        const float w = wsm[t];
        const float cprev = t ? cseq[t - 1] : 0.f;
        const bool fired = (cprev + w) >= 1.0f;
        const float cc = fired ? (1.0f - cprev) : w;
        const bool tail = (t == ps) && (cseq[t] > 0.6f);
        cc_bt[(size_t)b * TT + t] = cc;
        out_marks[(size_t)b * TT + t] = (fired || tail) ? 1.f : 0.f;
        qpart += w;
    }
#pragma unroll
    for (int s = 32; s >= 1; s >>= 1) qpart += __shfl_xor(qpart, s, 64);
    if (l == 0) { out_q[b] = qpart; nfr[b] = totF + tailAny; }
}

// ---------------------------------------------------------------------------
// Parallel frame materialization: block (j, b) -> compacted slot j of batch b.
__global__ __launch_bounds__(128) void cif_out_kernel(
    const float* __restrict__ x, const float* __restrict__ cc_bt,
    const float4* __restrict__ recs, const int* __restrict__ nfr,
    float* __restrict__ out_cif, float* __restrict__ out_mask) {
    const int j = blockIdx.x, b = blockIdx.y;
    const int l = threadIdx.x;
    const int m = nfr[b];
    float4 acc = make_float4(0.f, 0.f, 0.f, 0.f);
    const size_t obase = ((size_t)b * TT + j) * EE + l * 4;
    if (j < m) {
        const float4 r = recs[b * TT + j];
        const int t0 = __float_as_int(r.x);
        const int t1 = __float_as_int(r.y);
        const float fcoef = r.z, scale = r.w;
        for (int t = t0; t <= t1; ++t) {
            const float coeff = (t == t0) ? fcoef : cc_bt[(size_t)b * TT + t];
            const float4 xv = *(const float4*)&x[((size_t)t * BB + b) * EE + l * 4];
            acc.x = fmaf(coeff, xv.x, acc.x);
            acc.y = fmaf(coeff, xv.y, acc.y);
            acc.z = fmaf(coeff, xv.z, acc.z);
            acc.w = fmaf(coeff, xv.w, acc.w);
        }
        acc.x *= scale; acc.y *= scale; acc.z *= scale; acc.w *= scale;
        if (l == 0) out_mask[b * TT + j] = 1.f;
    } else {
        if (l == 0) out_mask[b * TT + j] = 0.f;
    }
    *(float4*)&out_cif[obase] = acc;
}

// ---------------------------------------------------------------------------
extern "C" void kernel_launch(void* const* d_in, const int* in_sizes, int n_in,
                              void* d_out, int out_size, void* d_ws, size_t ws_size,
                              hipStream_t stream) {
    const float* x    = (const float*)d_in[0];   // (T, B, E)
    const void*  pm   = d_in[1];                 // (B, T) bool -> int32 or bytes (detected)
    const float* W    = (const float*)d_in[2];   // (E, N)
    const float* bias = (const float*)d_in[3];   // (N,)
    const float* v    = (const float*)d_in[4];   // (N, 1)
    const float* vb   = (const float*)d_in[5];   // (1,)

    // workspace: same footprint class as the proven round-0 kernel (~1.5 MB)
    float* ws        = (float*)d_ws;
    float* weight_bt = ws;                                 // BB*TT
    float* cc_bt     = ws + (size_t)TT * BB;               // BB*TT
    float4* recs     = (float4*)(ws + 2 * (size_t)TT * BB);// BB*TT float4
    int* nfr         = (int*)(ws + 2 * (size_t)TT * BB + 4 * (size_t)BB * TT);
    int* ps          = nfr + BB;
    int* flag        = ps + BB;

    float* out_cif   = (float*)d_out;                     // (B, T, E)
    float* out_mask  = out_cif + (size_t)BB * TT * EE;    // (B, T)
    float* out_q     = out_mask + (size_t)BB * TT;        // (B,)
    float* out_marks = out_q + BB;                        // (B, T)

    // W-split scratch lives in out_cif (1 MB of 128 MB); gemm consumes it
    // before cif_out_kernel overwrites every byte of out_cif (stream-ordered).
    short* Whs = (short*)out_cif;                         // 512 KB
    short* Wls = Whs + (size_t)NN * EE;                   // 512 KB

    detect_mask_kernel<<<1, 1024, 0, stream>>>((const unsigned*)pm, flag);
    compute_ps_kernel<<<BB, 256, 0, stream>>>(pm, flag, ps);
    split_w_kernel<<<dim3(16, 16), 256, 0, stream>>>(W, Whs, Wls);
    gemm_weight_mfma<<<512, 256, 0, stream>>>(x, pm, flag, Whs, Wls, bias, v, vb, weight_bt);
    cif_scan_kernel<<<BB, 64, 0, stream>>>(weight_bt, ps, x, W, bias, v, vb,
                                           cc_bt, recs, nfr, out_q, out_marks);
    cif_out_kernel<<<dim3(TT, BB), 128, 0, stream>>>(x, cc_bt, recs, nfr, out_cif, out_mask);
}

// Round 6
// 489.974 us; speedup vs baseline: 1.9247x; 1.3114x over previous
//
#include <hip/hip_runtime.h>
#include <math.h>

#define TT 2048
#define BB 32
#define EE 512
#define NN 512

typedef short bf16x8 __attribute__((ext_vector_type(8)));
typedef float f32x4 __attribute__((ext_vector_type(4)));

__device__ __forceinline__ short bf16_rne(float x) {
    const unsigned u = __float_as_uint(x);
    return (short)((u + 0x7FFFu + ((u >> 16) & 1u)) >> 16);
}
__device__ __forceinline__ float bf16_f32(short h) {
    return __uint_as_float(((unsigned)(unsigned short)h) << 16);
}
__device__ __forceinline__ void gload_lds16(const void* g, void* l) {
    __builtin_amdgcn_global_load_lds((const __attribute__((address_space(1))) void*)g,
                                     (__attribute__((address_space(3))) void*)l, 16, 0, 0);
}

// ---------------------------------------------------------------------------
// padding_mask dtype detector: int32 0/1 words stay <=1; byte-bool rows are
// monotonic so any packed word is 0x01000000/0x01010000/0x01010101/... (>1).
__global__ void detect_mask_kernel(const unsigned* __restrict__ pm, int* __restrict__ flag) {
    __shared__ int s[1024];
    const int l = threadIdx.x;
    int bad = 0;
    for (int i = l; i < BB * TT; i += 1024) bad |= (pm[i] > 1u);
    s[l] = bad;
    __syncthreads();
    for (int st = 512; st > 0; st >>= 1) { if (l < st) s[l] |= s[l + st]; __syncthreads(); }
    if (l == 0) *flag = s[0];
}

__device__ __forceinline__ int pad_at(const void* pm, int idx, int isByte) {
    return isByte ? (int)(((const unsigned char*)pm)[idx] != 0)
                  : (int)(((const int*)pm)[idx] != 0);
}

// ---------------------------------------------------------------------------
// padding_start[b] = count of not-pad = lengths[b]
__global__ void compute_ps_kernel(const void* __restrict__ pm, const int* __restrict__ flag,
                                  int* __restrict__ ps) {
    __shared__ int s[256];
    const int b = blockIdx.x, l = threadIdx.x;
    const int isByte = *flag;
    int cnt = 0;
    for (int t = l; t < TT; t += 256) cnt += (pad_at(pm, b * TT + t, isByte) == 0);
    s[l] = cnt;
    __syncthreads();
    for (int st = 128; st > 0; st >>= 1) { if (l < st) s[l] += s[l + st]; __syncthreads(); }
    if (l == 0) ps[b] = s[0];
}

// ---------------------------------------------------------------------------
// One-time W split+transpose: W[E][N] fp32 -> Wh/Wl[N][E] bf16 (k contiguous),
// RNE hi + RNE residual lo. Scratch lives in out_cif (overwritten later).
__global__ __launch_bounds__(256) void split_w_kernel(const float* __restrict__ W,
                                                      short* __restrict__ Wh,
                                                      short* __restrict__ Wl) {
    __shared__ float tile[32][33];
    const int bn = blockIdx.x, bk = blockIdx.y;
    const int tx = threadIdx.x & 31, ty = threadIdx.x >> 5;
    for (int i = ty; i < 32; i += 8)
        tile[i][tx] = W[(size_t)(bk * 32 + i) * NN + bn * 32 + tx];
    __syncthreads();
    for (int i = ty; i < 32; i += 8) {
        const float val = tile[tx][i];
        const short h = bf16_rne(val);
        const short lo = bf16_rne(val - bf16_f32(h));
        const size_t o = (size_t)(bn * 32 + i) * EE + bk * 32 + tx;
        Wh[o] = h;
        Wl[o] = lo;
    }
}

// ---------------------------------------------------------------------------
// MFMA GEMM + fused relu/dot(v)/sigmoid/mask.  (unchanged, passed r2-r5)
__global__ __launch_bounds__(256, 2) void gemm_weight_mfma(
    const float* __restrict__ x, const void* __restrict__ pm, const int* __restrict__ flag,
    const short* __restrict__ Wh, const short* __restrict__ Wl,
    const float* __restrict__ bias, const float* __restrict__ v, const float* __restrict__ vb,
    float* __restrict__ weight_bt) {
    __shared__ __align__(16) short Ah[128 * 64];
    __shared__ __align__(16) short Al[128 * 64];
    __shared__ __align__(16) short Bh[128 * 64];
    __shared__ __align__(16) short Bl[128 * 64];
    __shared__ float bias_s[512], v_s[512];
    __shared__ float lsum[128][2];

    const int tid = threadIdx.x;
    const int l = tid & 63, wid = tid >> 6;
    const int wr = wid >> 1, wc = wid & 1;
    const int q = l >> 4, li = l & 15, x7 = l & 7;
    const int tp = blockIdx.x;

    for (int i = tid; i < 512; i += 256) { bias_s[i] = bias[i]; v_s[i] = v[i]; }

    const float* xblk = x + (size_t)tp * 128 * EE;
    const int arow = tid >> 1;
    const int akoff = (tid & 1) * 32;
    const int ac0 = akoff >> 3;
    const int aswz = arow & 7;

    float rowsum[4][4];
#pragma unroll
    for (int m = 0; m < 4; ++m)
#pragma unroll
        for (int r = 0; r < 4; ++r) rowsum[m][r] = 0.f;

    for (int nc = 0; nc < 4; ++nc) {
        const int n0 = nc * 128;
        f32x4 acc[4][4];
#pragma unroll
        for (int m = 0; m < 4; ++m)
#pragma unroll
            for (int n = 0; n < 4; ++n) acc[m][n] = (f32x4){0.f, 0.f, 0.f, 0.f};

        for (int k0 = 0; k0 < EE; k0 += 64) {
            __syncthreads();
#pragma unroll
            for (int i = 0; i < 4; ++i) {
                const int u = i * 256 + tid;
                const int row = u >> 3, c = u & 7;
                const int ge = (n0 + row) * EE + k0 + ((c ^ (row & 7)) << 3);
                gload_lds16(Wh + ge, &Bh[u * 8]);
                gload_lds16(Wl + ge, &Bl[u * 8]);
            }
            const float* xr = xblk + (size_t)arow * EE + k0 + akoff;
#pragma unroll
            for (int g = 0; g < 4; ++g) {
                float e[8];
                *(float4*)&e[0] = *(const float4*)&xr[g * 8];
                *(float4*)&e[4] = *(const float4*)&xr[g * 8 + 4];
                bf16x8 hv, lv;
#pragma unroll
                for (int j = 0; j < 8; ++j) {
                    const short h = bf16_rne(e[j]);
                    hv[j] = h;
                    lv[j] = bf16_rne(e[j] - bf16_f32(h));
                }
                const int p = arow * 64 + (((ac0 + g) ^ aswz) << 3);
                *(bf16x8*)&Ah[p] = hv;
                *(bf16x8*)&Al[p] = lv;
            }
            __syncthreads();
#pragma unroll
            for (int kf = 0; kf < 2; ++kf) {
                const int co = (((kf << 2) + q) ^ x7) << 3;
                bf16x8 ah[4], al[4];
#pragma unroll
                for (int m = 0; m < 4; ++m) {
                    const int ro = (wr * 64 + m * 16 + li) * 64 + co;
                    ah[m] = *(const bf16x8*)&Ah[ro];
                    al[m] = *(const bf16x8*)&Al[ro];
                }
#pragma unroll
                for (int n = 0; n < 4; ++n) {
                    const int bo = (wc * 64 + n * 16 + li) * 64 + co;
                    const bf16x8 bh = *(const bf16x8*)&Bh[bo];
                    const bf16x8 bl = *(const bf16x8*)&Bl[bo];
#pragma unroll
                    for (int m = 0; m < 4; ++m) {
                        acc[m][n] = __builtin_amdgcn_mfma_f32_16x16x32_bf16(ah[m], bh, acc[m][n], 0, 0, 0);
                        acc[m][n] = __builtin_amdgcn_mfma_f32_16x16x32_bf16(al[m], bh, acc[m][n], 0, 0, 0);
                        acc[m][n] = __builtin_amdgcn_mfma_f32_16x16x32_bf16(ah[m], bl, acc[m][n], 0, 0, 0);
                    }
                }
            }
        }
#pragma unroll
        for (int m = 0; m < 4; ++m)
#pragma unroll
            for (int n = 0; n < 4; ++n) {
                const int col = n0 + wc * 64 + n * 16 + li;
                const float bcol = bias_s[col], vcol = v_s[col];
#pragma unroll
                for (int r = 0; r < 4; ++r) {
                    const float h = fmaxf(acc[m][n][r] + bcol, 0.f);
                    rowsum[m][r] = fmaf(h, vcol, rowsum[m][r]);
                }
            }
    }
#pragma unroll
    for (int m = 0; m < 4; ++m)
#pragma unroll
        for (int r = 0; r < 4; ++r) {
            float s = rowsum[m][r];
            s += __shfl_xor(s, 1, 64);
            s += __shfl_xor(s, 2, 64);
            s += __shfl_xor(s, 4, 64);
            s += __shfl_xor(s, 8, 64);
            rowsum[m][r] = s;
        }
    if (li == 0) {
#pragma unroll
        for (int m = 0; m < 4; ++m)
#pragma unroll
            for (int r = 0; r < 4; ++r)
                lsum[wr * 64 + m * 16 + q * 4 + r][wc] = rowsum[m][r];
    }
    __syncthreads();
    if (tid < 128) {
        const int isByte = *flag;
        const float logit = lsum[tid][0] + lsum[tid][1] + *vb;
        const float wg = 1.0f / (1.0f + expf(-logit));
        const int gr = tp * 128 + tid;
        const int t = gr >> 5, b = gr & 31;
        weight_bt[(size_t)b * TT + t] = pad_at(pm, b * TT + t, isByte) ? 0.f : wg;
    }
}

// ---------------------------------------------------------------------------
// Scan v5 (serial half): minimal serial core + BATCHED band rescue.
// Insight: a fix shifts w by d~4e-6; dc'/dc=1 on both branches so downstream
// margins shift by <=d << BAND -> no downstream decision changes unless the
// FIXED step's own decision flips (P~8%/event). So: one pass, detect ALL
// events, fp32-fix all (fast 8-col/lane GEMV), flip-check against existing
// cseq; re-pass ONLY on an actual flip (expected ~0.16/run -> usually zero).
// Derivation (P1-P4) moved to cif_derive_kernel for separate rocprof timing;
// cseq is dumped to scratch inside out_cif (overwritten later by cif_out).
#define BAND 5e-5f
#define MAXEV 32
__global__ __launch_bounds__(64) void cif_scan_kernel(
    float* __restrict__ weight_bt,
    const float* __restrict__ x, const float* __restrict__ W,
    const float* __restrict__ bias, const float* __restrict__ v,
    const float* __restrict__ vb,
    float* __restrict__ cseq_g) {
    __shared__ __align__(16) float wsm[TT];
    __shared__ __align__(16) float cseq[TT];
    __shared__ __align__(16) float xrow[EE];
    __shared__ int evl_s[MAXEV];
    __shared__ float wfix_s[MAXEV];
    __shared__ unsigned fixedbm[TT / 32];
    const int b = blockIdx.x, l = threadIdx.x;
    float* wrow = weight_bt + (size_t)b * TT;

    for (int t = l * 8; t < TT; t += 64 * 8) {
        *(float4*)&wsm[t]     = *(const float4*)&wrow[t];
        *(float4*)&wsm[t + 4] = *(const float4*)&wrow[t + 4];
    }
    fixedbm[l] = 0u;                         // word l covers t in [l*32, l*32+32)
    __syncthreads();

    int t0s = 0;
    for (int iter = 0; iter < 64; ++iter) {
        if (l == 0) {
            // minimal branchless serial recurrence, depth-2 LDS prefetch
            float c = (t0s > 0) ? cseq[t0s - 1] : 0.f;
            float4 n1a = *(const float4*)&wsm[t0s];
            float4 n1b = *(const float4*)&wsm[t0s + 4];
            const int tp8 = (t0s + 8) & (TT - 1);
            float4 n2a = *(const float4*)&wsm[tp8];
            float4 n2b = *(const float4*)&wsm[tp8 + 4];
            for (int t = t0s; t < TT; t += 8) {
                const float4 wa = n1a, wb = n1b;
                n1a = n2a; n1b = n2b;
                const int tn = (t + 16) & (TT - 1);
                n2a = *(const float4*)&wsm[tn];
                n2b = *(const float4*)&wsm[tn + 4];
                const float wv[8] = {wa.x, wa.y, wa.z, wa.w, wb.x, wb.y, wb.z, wb.w};
                float cs[8];
#pragma unroll
                for (int u = 0; u < 8; ++u) {
                    const float w = wv[u];
                    const float a = 1.0f - c;
                    const float s = c + w;
                    const float bb = w - a;
                    c = (s >= 1.0f) ? bb : s;
                    cs[u] = c;
                }
                *(float4*)&cseq[t]     = make_float4(cs[0], cs[1], cs[2], cs[3]);
                *(float4*)&cseq[t + 4] = make_float4(cs[4], cs[5], cs[6], cs[7]);
            }
        }
        __syncthreads();
        // --- detect ALL unfixed band events (contiguous 32 t's per lane)
        const int base = l * 32;
        const unsigned fixw = fixedbm[l];
        unsigned hm = 0u;
        for (int u = 0; u < 32; ++u) {
            const int t = base + u;
            const float w = wsm[t];
            if (w > 0.f && !((fixw >> u) & 1u)) {
                const float cprev = t ? cseq[t - 1] : 0.f;
                if (fabsf(cprev + w - 1.0f) < BAND) hm |= (1u << u);
            }
        }
        unsigned long long bal = __ballot(hm != 0u);
        int nev = 0;
        while (bal != 0ull && nev < MAXEV) {        // uniform extraction, ordered
            const int src = __ffsll((unsigned long long)bal) - 1;
            unsigned hs = __shfl(hm, src, 64);
            while (hs != 0u && nev < MAXEV) {
                const int u = __ffs(hs) - 1;
                if (l == 0) evl_s[nev] = src * 32 + u;
                ++nev;
                hs &= hs - 1u;
            }
            bal &= bal - 1ull;
        }
        __syncthreads();
        if (nev == 0) break;
        // --- batched fp32 GEMV fixes: lane owns cols l*8..l*8+7, 2xfloat4/row
        const float4 v0 = *(const float4*)&v[l * 8];
        const float4 v1 = *(const float4*)&v[l * 8 + 4];
        const float4 bi0 = *(const float4*)&bias[l * 8];
        const float4 bi1 = *(const float4*)&bias[l * 8 + 4];
        for (int k = 0; k < nev; ++k) {
            const int ev = evl_s[k];
            const float* xr = &x[((size_t)ev * BB + b) * EE];
            *(float4*)&xrow[l * 8]     = *(const float4*)&xr[l * 8];
            *(float4*)&xrow[l * 8 + 4] = *(const float4*)&xr[l * 8 + 4];
            __syncthreads();
            float h[8] = {bi0.x, bi0.y, bi0.z, bi0.w, bi1.x, bi1.y, bi1.z, bi1.w};
#pragma unroll 4
            for (int e = 0; e < EE; ++e) {
                const float xe = xrow[e];
                const float4 w0 = *(const float4*)&W[(size_t)e * NN + l * 8];
                const float4 w1 = *(const float4*)&W[(size_t)e * NN + l * 8 + 4];
                h[0] = fmaf(xe, w0.x, h[0]); h[1] = fmaf(xe, w0.y, h[1]);
                h[2] = fmaf(xe, w0.z, h[2]); h[3] = fmaf(xe, w0.w, h[3]);
                h[4] = fmaf(xe, w1.x, h[4]); h[5] = fmaf(xe, w1.y, h[5]);
                h[6] = fmaf(xe, w1.z, h[6]); h[7] = fmaf(xe, w1.w, h[7]);
            }
            float part = fmaxf(h[0], 0.f) * v0.x;
            part = fmaf(fmaxf(h[1], 0.f), v0.y, part);
            part = fmaf(fmaxf(h[2], 0.f), v0.z, part);
            part = fmaf(fmaxf(h[3], 0.f), v0.w, part);
            part = fmaf(fmaxf(h[4], 0.f), v1.x, part);
            part = fmaf(fmaxf(h[5], 0.f), v1.y, part);
            part = fmaf(fmaxf(h[6], 0.f), v1.z, part);
            part = fmaf(fmaxf(h[7], 0.f), v1.w, part);
#pragma unroll
            for (int s = 32; s >= 1; s >>= 1) part += __shfl_xor(part, s, 64);
            if (l == 0) wfix_s[k] = 1.0f / (1.0f + expf(-(part + *vb)));
            __syncthreads();
        }
        // --- apply fixes + flip check (uniform across lanes)
        int firstflip = -1;
        for (int k = 0; k < nev; ++k) {
            const int ev = evl_s[k];
            const float wnew = wfix_s[k];
            const float cprev = ev ? cseq[ev - 1] : 0.f;
            const bool of = (cprev + wsm[ev]) >= 1.0f;
            const bool nf = (cprev + wnew) >= 1.0f;
            if (l == 0) {
                wsm[ev] = wnew;
                wrow[ev] = wnew;                    // publish for derive kernel
                fixedbm[ev >> 5] |= (1u << (ev & 31));
            }
            if (nf != of && firstflip < 0) firstflip = ev;
        }
        __syncthreads();
        if (firstflip < 0) break;                   // values off by d<<tol: done
        t0s = firstflip & ~7;                       // structural change: re-pass
    }
    __syncthreads();
    // dump cseq for the derive kernel
    for (int t = l * 8; t < TT; t += 64 * 8) {
        *(float4*)&cseq_g[(size_t)b * TT + t]     = *(const float4*)&cseq[t];
        *(float4*)&cseq_g[(size_t)b * TT + t + 4] = *(const float4*)&cseq[t + 4];
    }
}

// ---------------------------------------------------------------------------
// Scan v5 (parallel half): P1-P4 derivation, verbatim from the passing r5
// code, reading wsm/cseq from global. Separate kernel => separate rocprof row.
__global__ __launch_bounds__(64) void cif_derive_kernel(
    const float* __restrict__ weight_bt, const float* __restrict__ cseq_g,
    const int* __restrict__ ps_arr,
    float* __restrict__ cc_bt, float4* __restrict__ recs,
    int* __restrict__ nfr, float* __restrict__ out_q, float* __restrict__ out_marks) {
    __shared__ __align__(16) float wsm[TT];
    __shared__ __align__(16) float cseq[TT];
    const int b = blockIdx.x, l = threadIdx.x;
    const int ps = ps_arr[b];
    for (int t = l * 8; t < TT; t += 64 * 8) {
        *(float4*)&wsm[t]      = *(const float4*)&weight_bt[(size_t)b * TT + t];
        *(float4*)&wsm[t + 4]  = *(const float4*)&weight_bt[(size_t)b * TT + t + 4];
        *(float4*)&cseq[t]     = *(const float4*)&cseq_g[(size_t)b * TT + t];
        *(float4*)&cseq[t + 4] = *(const float4*)&cseq_g[(size_t)b * TT + t + 4];
    }
    __syncthreads();

    // P1: per-lane contiguous 32-step range -> fired bitmask
    const int base = l * 32;
    unsigned fmask = 0u;
    for (int u = 0; u < 32; ++u) {
        const int t = base + u;
        const float cprev = t ? cseq[t - 1] : 0.f;
        if (cprev + wsm[t] >= 1.0f) fmask |= (1u << u);
    }
    const int myF = __popc(fmask);
    int myLast = fmask ? (base + (31 - __clz(fmask))) : -1;

    // P2: wave scans
    int inc = myF;
#pragma unroll
    for (int off = 1; off < 64; off <<= 1) {
        const int n = __shfl_up(inc, off, 64);
        if (l >= off) inc += n;
    }
    const int exF = inc - myF;
    const int totF = __shfl(inc, 63, 64);
    int incLast = myLast;
#pragma unroll
    for (int off = 1; off < 64; off <<= 1) {
        const int n = __shfl_up(incLast, off, 64);
        if (l >= off) incLast = (incLast > n) ? incLast : n;
    }
    int prevFire = __shfl_up(incLast, 1, 64);
    if (l == 0) prevFire = -1;
    int tf = (prevFire > 0) ? prevFire : 0;

    // P3: emit fire recs; capture tail rec at t==ps
    int slot = exF;
    int tailWrote = 0;
    for (int u = 0; u < 32; ++u) {
        const int t = base + u;
        if (fmask & (1u << u)) {
            recs[(size_t)b * TT + slot] =
                make_float4(__int_as_float(tf), __int_as_float(t), cseq[tf], 1.0f);
            ++slot;
            tf = t;
        }
        if (t == ps) {
            const float cw = cseq[t];
            if (cw > 0.6f && totF < TT) {
                recs[(size_t)b * TT + totF] =
                    make_float4(__int_as_float(tf), __int_as_float(t - 1), cseq[tf],
                                1.0f / (cw + 1e-10f));
                tailWrote = 1;
            }
        }
    }
    const int tailAny = (__ballot(tailWrote) != 0ull) ? 1 : 0;

    // P4: coalesced cc / marks / qsum
    float qpart = 0.f;
    for (int t = l; t < TT; t += 64) {
        const float w = wsm[t];
        const float cprev = t ? cseq[t - 1] : 0.f;
        const bool fired = (cprev + w) >= 1.0f;
        const float cc = fired ? (1.0f - cprev) : w;
        const bool tail = (t == ps) && (cseq[t] > 0.6f);
        cc_bt[(size_t)b * TT + t] = cc;
        out_marks[(size_t)b * TT + t] = (fired || tail) ? 1.f : 0.f;
        qpart += w;
    }
#pragma unroll
    for (int s = 32; s >= 1; s >>= 1) qpart += __shfl_xor(qpart, s, 64);
    if (l == 0) { out_q[b] = qpart; nfr[b] = totF + tailAny; }
}

// ---------------------------------------------------------------------------
// Parallel frame materialization: block (j, b) -> compacted slot j of batch b.
__global__ __launch_bounds__(128) void cif_out_kernel(
    const float* __restrict__ x, const float* __restrict__ cc_bt,
    const float4* __restrict__ recs, const int* __restrict__ nfr,
    float* __restrict__ out_cif, float* __restrict__ out_mask) {
    const int j = blockIdx.x, b = blockIdx.y;
    const int l = threadIdx.x;
    const int m = nfr[b];
    float4 acc = make_float4(0.f, 0.f, 0.f, 0.f);
    const size_t obase = ((size_t)b * TT + j) * EE + l * 4;
    if (j < m) {
        const float4 r = recs[b * TT + j];
        const int t0 = __float_as_int(r.x);
        const int t1 = __float_as_int(r.y);
        const float fcoef = r.z, scale = r.w;
        for (int t = t0; t <= t1; ++t) {
            const float coeff = (t == t0) ? fcoef : cc_bt[(size_t)b * TT + t];
            const float4 xv = *(const float4*)&x[((size_t)t * BB + b) * EE + l * 4];
            acc.x = fmaf(coeff, xv.x, acc.x);
            acc.y = fmaf(coeff, xv.y, acc.y);
            acc.z = fmaf(coeff, xv.z, acc.z);
            acc.w = fmaf(coeff, xv.w, acc.w);
        }
        acc.x *= scale; acc.y *= scale; acc.z *= scale; acc.w *= scale;
        if (l == 0) out_mask[b * TT + j] = 1.f;
    } else {
        if (l == 0) out_mask[b * TT + j] = 0.f;
    }
    *(float4*)&out_cif[obase] = acc;
}

// ---------------------------------------------------------------------------
extern "C" void kernel_launch(void* const* d_in, const int* in_sizes, int n_in,
                              void* d_out, int out_size, void* d_ws, size_t ws_size,
                              hipStream_t stream) {
    const float* x    = (const float*)d_in[0];   // (T, B, E)
    const void*  pm   = d_in[1];                 // (B, T) bool -> int32 or bytes (detected)
    const float* W    = (const float*)d_in[2];   // (E, N)
    const float* bias = (const float*)d_in[3];   // (N,)
    const float* v    = (const float*)d_in[4];   // (N, 1)
    const float* vb   = (const float*)d_in[5];   // (1,)

    // workspace: same footprint class as the proven round-0 kernel (~1.5 MB)
    float* ws        = (float*)d_ws;
    float* weight_bt = ws;                                 // BB*TT
    float* cc_bt     = ws + (size_t)TT * BB;               // BB*TT
    float4* recs     = (float4*)(ws + 2 * (size_t)TT * BB);// BB*TT float4
    int* nfr         = (int*)(ws + 2 * (size_t)TT * BB + 4 * (size_t)BB * TT);
    int* ps          = nfr + BB;
    int* flag        = ps + BB;

    float* out_cif   = (float*)d_out;                     // (B, T, E)
    float* out_mask  = out_cif + (size_t)BB * TT * EE;    // (B, T)
    float* out_q     = out_mask + (size_t)BB * TT;        // (B,)
    float* out_marks = out_q + BB;                        // (B, T)

    // Scratch inside out_cif (128 MB, fully overwritten by cif_out_kernel):
    // [0, 1MB): Wh/Wl bf16 split; [2MB, 2.25MB): cseq dump. Stream-ordered.
    short* Whs    = (short*)out_cif;                      // 512 KB
    short* Wls    = Whs + (size_t)NN * EE;                // 512 KB
    float* cseq_g = (float*)((char*)out_cif + (2u << 20));// 256 KB

    detect_mask_kernel<<<1, 1024, 0, stream>>>((const unsigned*)pm, flag);
    compute_ps_kernel<<<BB, 256, 0, stream>>>(pm, flag, ps);
    split_w_kernel<<<dim3(16, 16), 256, 0, stream>>>(W, Whs, Wls);
    gemm_weight_mfma<<<512, 256, 0, stream>>>(x, pm, flag, Whs, Wls, bias, v, vb, weight_bt);
    cif_scan_kernel<<<BB, 64, 0, stream>>>(weight_bt, x, W, bias, v, vb, cseq_g);
    cif_derive_kernel<<<BB, 64, 0, stream>>>(weight_bt, cseq_g, ps, cc_bt, recs,
                                             nfr, out_q, out_marks);
    cif_out_kernel<<<dim3(TT, BB), 128, 0, stream>>>(x, cc_bt, recs, nfr, out_cif, out_mask);
}